// Round 1
// baseline (1114.414 us; speedup 1.0000x reference)
//
#include <hip/hip_runtime.h>
#include <math.h>

// ---------------------------------------------------------------------------
// MemoryAugmentedNetwork — f32 baseline
// Shapes: B=2048, IN=1024, E=512, M=256, NB=8, H=8, D=64
// Algebraic simplifications (exact in real arithmetic):
//  * MHA1 K/V = broadcast memory -> shared kp/vp (256x512)
//  * u = mean_q(attended) = (mean_q ctx) @ out_w^T + out_b   (mean commutes)
//  * MHA2 K/V rows = memory[m] + u[b]:
//      scores: dot(q, uk[b]) const over m -> drops out of softmax
//      ctx2 = sum_m attn*Vm[m] + uv[b]                  (sum attn = 1)
// Scores scratch lives in the updated_memory region of d_out (written last).
// ---------------------------------------------------------------------------

// ------------------------- generic batched SGEMM ---------------------------
// C[z][m][n] = act( scale * sum_k A[z][m][k]*B[z][n][k] + bias[n] )
// A: lda row stride, sA batch stride (elements). Same for B, C.
template<int ACT>
__global__ __launch_bounds__(256)
void sgemm(const float* __restrict__ A, int lda, long long sA,
           const float* __restrict__ B, int ldb, long long sB,
           const float* __restrict__ bias,
           float* __restrict__ C, int ldc, long long sC,
           int M, int N, int K, float scale)
{
    constexpr int BM = 128, BN = 64, BK = 16;
    __shared__ float As[BK][BM + 4];
    __shared__ float Bs[BK][BN + 4];
    A += (long long)blockIdx.z * sA;
    B += (long long)blockIdx.z * sB;
    C += (long long)blockIdx.z * sC;
    const int m0 = blockIdx.x * BM;
    const int n0 = blockIdx.y * BN;
    const int t  = threadIdx.x;
    const int tx = t & 15;   // n quad
    const int ty = t >> 4;   // m octet
    const int ar = t >> 2;          // 0..63 (rows; +64 for second load)
    const int ac = (t & 3) << 2;    // k within BK
    const int br = t >> 2;          // 0..63
    const int bc = (t & 3) << 2;

    float acc[8][4] = {};

    for (int k0 = 0; k0 < K; k0 += BK) {
        __syncthreads();
        float4 a0 = *reinterpret_cast<const float4*>(A + (long long)(m0 + ar) * lda + k0 + ac);
        float4 a1 = *reinterpret_cast<const float4*>(A + (long long)(m0 + ar + 64) * lda + k0 + ac);
        float4 b0 = *reinterpret_cast<const float4*>(B + (long long)(n0 + br) * ldb + k0 + bc);
        As[ac+0][ar] = a0.x; As[ac+1][ar] = a0.y; As[ac+2][ar] = a0.z; As[ac+3][ar] = a0.w;
        As[ac+0][ar+64] = a1.x; As[ac+1][ar+64] = a1.y; As[ac+2][ar+64] = a1.z; As[ac+3][ar+64] = a1.w;
        Bs[bc+0][br] = b0.x; Bs[bc+1][br] = b0.y; Bs[bc+2][br] = b0.z; Bs[bc+3][br] = b0.w;
        __syncthreads();
        #pragma unroll
        for (int k = 0; k < BK; ++k) {
            float4 av0 = *reinterpret_cast<const float4*>(&As[k][ty * 8]);
            float4 av1 = *reinterpret_cast<const float4*>(&As[k][ty * 8 + 4]);
            float4 bv  = *reinterpret_cast<const float4*>(&Bs[k][tx * 4]);
            float am[8] = {av0.x, av0.y, av0.z, av0.w, av1.x, av1.y, av1.z, av1.w};
            float bm[4] = {bv.x, bv.y, bv.z, bv.w};
            #pragma unroll
            for (int i = 0; i < 8; ++i)
                #pragma unroll
                for (int j = 0; j < 4; ++j)
                    acc[i][j] = fmaf(am[i], bm[j], acc[i][j]);
        }
    }

    float bb[4] = {0.f, 0.f, 0.f, 0.f};
    if (bias) {
        bb[0] = bias[n0 + tx*4 + 0];
        bb[1] = bias[n0 + tx*4 + 1];
        bb[2] = bias[n0 + tx*4 + 2];
        bb[3] = bias[n0 + tx*4 + 3];
    }
    #pragma unroll
    for (int i = 0; i < 8; ++i) {
        int row = m0 + ty * 8 + i;
        float o0 = acc[i][0] * scale + bb[0];
        float o1 = acc[i][1] * scale + bb[1];
        float o2 = acc[i][2] * scale + bb[2];
        float o3 = acc[i][3] * scale + bb[3];
        if (ACT) { o0 = tanhf(o0); o1 = tanhf(o1); o2 = tanhf(o2); o3 = tanhf(o3); }
        float4 o4 = {o0, o1, o2, o3};
        *reinterpret_cast<float4*>(C + (long long)row * ldc + n0 + tx * 4) = o4;
    }
}

// --------------------- softmax over contiguous rows of 256 ------------------
__global__ __launch_bounds__(256)
void softmax256(float* __restrict__ S, int nrows)
{
    int wave = threadIdx.x >> 6;
    int lane = threadIdx.x & 63;
    long long row = (long long)blockIdx.x * 4 + wave;
    if (row >= nrows) return;
    float4* p = reinterpret_cast<float4*>(S + row * 256) + lane;
    float4 v = *p;
    float mx = fmaxf(fmaxf(v.x, v.y), fmaxf(v.z, v.w));
    #pragma unroll
    for (int off = 32; off > 0; off >>= 1)
        mx = fmaxf(mx, __shfl_xor(mx, off, 64));
    v.x = expf(v.x - mx); v.y = expf(v.y - mx);
    v.z = expf(v.z - mx); v.w = expf(v.w - mx);
    float sm = v.x + v.y + v.z + v.w;
    #pragma unroll
    for (int off = 32; off > 0; off >>= 1)
        sm += __shfl_xor(sm, off, 64);
    float inv = 1.0f / sm;
    v.x *= inv; v.y *= inv; v.z *= inv; v.w *= inv;
    *p = v;
}

// vpT[h][d][m] = kv[m][512 + h*64 + d]   (kv rows: [kp(512) | vp(512)])
__global__ __launch_bounds__(256)
void transpose_vp(const float* __restrict__ kv, float* __restrict__ vpT)
{
    int idx = blockIdx.x * 256 + threadIdx.x;   // 8*64*256 = 131072
    int m = idx & 255;
    int rest = idx >> 8;
    int d = rest & 63;
    int h = rest >> 6;
    vpT[idx] = kv[m * 1024 + 512 + h * 64 + d];
}

// cbar[b][h*64+d] = (1/8) sum_q ctx1[h][b*8+q][d]
__global__ __launch_bounds__(256)
void mean_ctx(const float* __restrict__ ctx1, float* __restrict__ cbar)
{
    int idx = blockIdx.x * 256 + threadIdx.x;   // 2048*512
    int e = idx & 511, b = idx >> 9;
    int h = e >> 6, d = e & 63;
    const float* p = ctx1 + (long long)h * 1048576 + (long long)b * 512 + d;
    float s = 0.f;
    #pragma unroll
    for (int q = 0; q < 8; ++q) s += p[q * 64];
    cbar[idx] = s * 0.125f;
}

// ctx2[b][h*64+d] = ctx2h[h][b][d] + uv[b][h*64+d]
__global__ __launch_bounds__(256)
void combine_ctx2(const float* __restrict__ ctx2h, const float* __restrict__ uv,
                  float* __restrict__ ctx2)
{
    int idx = blockIdx.x * 256 + threadIdx.x;   // 2048*512
    int e = idx & 511, b = idx >> 9;
    int h = e >> 6, d = e & 63;
    ctx2[idx] = ctx2h[(long long)h * 131072 + b * 64 + d] + uv[idx];
}

// out1[b][m][e] = memory[m][e] + u[b][e]   (float4 over e)
__global__ __launch_bounds__(256)
void write_out1(const float* __restrict__ mem, const float* __restrict__ u,
                float* __restrict__ out1)
{
    const float4* m4 = reinterpret_cast<const float4*>(mem);
    const float4* u4 = reinterpret_cast<const float4*>(u);
    float4* o4 = reinterpret_cast<float4*>(out1);
    const long long total = 2048LL * 256 * 128;
    for (long long i = (long long)blockIdx.x * 256 + threadIdx.x; i < total;
         i += (long long)gridDim.x * 256) {
        int e4 = (int)(i & 127);
        int m  = (int)((i >> 7) & 255);
        long long b = i >> 15;
        float4 a = m4[m * 128 + e4];
        float4 c = u4[b * 128 + e4];
        float4 r = {a.x + c.x, a.y + c.y, a.z + c.z, a.w + c.w};
        o4[i] = r;
    }
}

extern "C" void kernel_launch(void* const* d_in, const int* in_sizes, int n_in,
                              void* d_out, int out_size, void* d_ws, size_t ws_size,
                              hipStream_t stream)
{
    (void)in_sizes; (void)n_in; (void)out_size; (void)ws_size;
    const float* x     = (const float*)d_in[0];
    const float* mem   = (const float*)d_in[1];
    const float* enc_w = (const float*)d_in[2];
    const float* enc_b = (const float*)d_in[3];
    const float* blk_w = (const float*)d_in[4];
    const float* blk_b = (const float*)d_in[5];
    const float* in_w  = (const float*)d_in[6];
    const float* in_b  = (const float*)d_in[7];
    const float* out_w = (const float*)d_in[8];
    const float* out_b = (const float*)d_in[9];
    const float* dec_w = (const float*)d_in[10];
    const float* dec_b = (const float*)d_in[11];
    float* out = (float*)d_out;
    float* w   = (float*)d_ws;

    // workspace layout (floats); total 18,219,008 f = 72.9 MB
    float* enc   = w;                  // 1,048,576
    float* Areg  = w + 1048576;        // 8,388,608: mu, then ctx1, then ctx2h
    float* Breg  = w + 9437184;        // 8,388,608: qp1, then small tensors
    float* kv    = w + 17825792;       // 262,144  (256 x [kp|vp])
    float* vpT   = w + 18087936;       // 131,072  ([h][d][m])
    float* mu    = Areg;
    float* ctx1  = Areg;
    float* ctx2h = Areg;
    float* qp1   = Breg;
    float* cbar  = Breg;               // reuses qp1 space (qp1 dead after scores1)
    float* u     = Breg + 1048576;
    float* qp2   = Breg + 2097152;
    float* uvb   = Breg + 3145728;
    float* ctx2  = Breg + 4194304;
    float* retr  = Breg + 5242880;
    // scores scratch = updated_memory region of d_out (written at the end)
    float* S     = out + 2097152;
    float* out1  = out + 2097152;

    dim3 blk(256);

    // 1. encoded = tanh(x @ enc_w^T + enc_b)            (2048x512, K=1024)
    sgemm<1><<<dim3(16, 8, 1), blk, 0, stream>>>(x, 1024, 0, enc_w, 1024, 0, enc_b,
                                                 enc, 512, 0, 2048, 512, 1024, 1.0f);
    // 2. mu = encoded @ blk_w^T + blk_b                 (2048x4096, K=512)
    sgemm<0><<<dim3(16, 64, 1), blk, 0, stream>>>(enc, 512, 0, blk_w, 512, 0, blk_b,
                                                  mu, 4096, 0, 2048, 4096, 512, 1.0f);
    // 3. qp1 = mu(view 16384x512) @ wq^T + bq
    sgemm<0><<<dim3(128, 8, 1), blk, 0, stream>>>(mu, 512, 0, in_w, 512, 0, in_b,
                                                  qp1, 512, 0, 16384, 512, 512, 1.0f);
    // 4. kv = memory @ [wk|wv]^T + [bk|bv]              (256x1024, K=512)
    sgemm<0><<<dim3(2, 16, 1), blk, 0, stream>>>(mem, 512, 0, in_w + 512 * 512, 512, 0,
                                                 in_b + 512, kv, 1024, 0, 256, 1024, 512, 1.0f);
    // 5. vpT[h][d][m]
    transpose_vp<<<dim3(512), blk, 0, stream>>>(kv, vpT);
    // 6. scores1[h][bq][m] = 0.125 * qp1_h @ kp_h^T     (z=8, K=64)
    sgemm<0><<<dim3(128, 4, 8), blk, 0, stream>>>(qp1, 512, 64, kv, 1024, 64, nullptr,
                                                  S, 256, 16384LL * 256, 16384, 256, 64, 0.125f);
    // 7. softmax over m
    softmax256<<<dim3(32768), blk, 0, stream>>>(S, 131072);
    // 8. ctx1[h][bq][d] = attn_h @ vpT_h^T              (z=8, K=256)
    sgemm<0><<<dim3(128, 1, 8), blk, 0, stream>>>(S, 256, 16384LL * 256, vpT, 256, 16384,
                                                  nullptr, ctx1, 64, 16384LL * 64,
                                                  16384, 64, 256, 1.0f);
    // 9. cbar = mean_q ctx1
    mean_ctx<<<dim3(4096), blk, 0, stream>>>(ctx1, cbar);
    // 10. u = cbar @ out_w^T + out_b
    sgemm<0><<<dim3(16, 8, 1), blk, 0, stream>>>(cbar, 512, 0, out_w, 512, 0, out_b,
                                                 u, 512, 0, 2048, 512, 512, 1.0f);
    // 11. qp2 = encoded @ wq^T + bq
    sgemm<0><<<dim3(16, 8, 1), blk, 0, stream>>>(enc, 512, 0, in_w, 512, 0, in_b,
                                                 qp2, 512, 0, 2048, 512, 512, 1.0f);
    // 12. uv = u @ wv^T (no bias; bv already inside vp)
    sgemm<0><<<dim3(16, 8, 1), blk, 0, stream>>>(u, 512, 0, in_w + 2 * 512 * 512, 512, 0,
                                                 nullptr, uvb, 512, 0, 2048, 512, 512, 1.0f);
    // 13. scores2[h][b][m] = 0.125 * qp2_h @ kp_h^T  (uk[b] term is softmax-invariant)
    sgemm<0><<<dim3(16, 4, 8), blk, 0, stream>>>(qp2, 512, 64, kv, 1024, 64, nullptr,
                                                 S, 256, 2048LL * 256, 2048, 256, 64, 0.125f);
    // 14. softmax
    softmax256<<<dim3(4096), blk, 0, stream>>>(S, 16384);
    // 15. ctx2h[h][b][d] = attn2_h @ vpT_h^T
    sgemm<0><<<dim3(16, 1, 8), blk, 0, stream>>>(S, 256, 2048LL * 256, vpT, 256, 16384,
                                                 nullptr, ctx2h, 64, 2048LL * 64,
                                                 2048, 64, 256, 1.0f);
    // 16. updated_memory output (overwrites scores scratch) — after last S use
    write_out1<<<dim3(4096), blk, 0, stream>>>(mem, u, out1);
    // 17. ctx2 = ctx2h + uv
    combine_ctx2<<<dim3(4096), blk, 0, stream>>>(ctx2h, uvb, ctx2);
    // 18. retrieved = ctx2 @ out_w^T + out_b
    sgemm<0><<<dim3(16, 8, 1), blk, 0, stream>>>(ctx2, 512, 0, out_w, 512, 0, out_b,
                                                 retr, 512, 0, 2048, 512, 512, 1.0f);
    // 19. output = retrieved @ dec_w^T + dec_b  -> d_out[0 : 2048*1024]
    sgemm<0><<<dim3(16, 16, 1), blk, 0, stream>>>(retr, 512, 0, dec_w, 512, 0, dec_b,
                                                  out, 1024, 0, 2048, 1024, 512, 1.0f);
}

// Round 2
// 741.998 us; speedup vs baseline: 1.5019x; 1.5019x over previous
//
#include <hip/hip_runtime.h>
#include <math.h>

// ---------------------------------------------------------------------------
// MemoryAugmentedNetwork — split-bf16 MFMA version
// Shapes: B=2048, IN=1024, E=512, M=256, NB=8, H=8, D=64
// Algebraic simplifications (exact): see R1. New in R2: every GEMM runs on
// mfma_f32_16x16x32_bf16 with split precision a = a_hi + a_lo (bf16 each),
// C = Ah*Bh + Ah*Bl + Al*Bh  (f32 accum) -> ~2^-18 relative input error,
// preserving the measured 2.4e-4 absmax.
// ---------------------------------------------------------------------------

typedef __attribute__((ext_vector_type(8))) short short8;
typedef __attribute__((ext_vector_type(4))) float f32x4;
typedef unsigned short u16;

__device__ inline u16 bf16_rn(float x) {
    unsigned u = __float_as_uint(x);
    unsigned r = (u + 0x7FFFu + ((u >> 16) & 1u)) >> 16;
    return (u16)r;
}
__device__ inline float bf16_f(u16 h) { return __uint_as_float(((unsigned)h) << 16); }

// ---------------- f32 -> (hi, lo) bf16 planes, vectorized ------------------
__global__ __launch_bounds__(256)
void split_f32(const float* __restrict__ in, u16* __restrict__ hi,
               u16* __restrict__ lo, long long n4)
{
    for (long long i = (long long)blockIdx.x * 256 + threadIdx.x; i < n4;
         i += (long long)gridDim.x * 256) {
        float4 v = reinterpret_cast<const float4*>(in)[i];
        u16 h0 = bf16_rn(v.x), h1 = bf16_rn(v.y), h2 = bf16_rn(v.z), h3 = bf16_rn(v.w);
        ushort4 hv = {h0, h1, h2, h3};
        ushort4 lv = {bf16_rn(v.x - bf16_f(h0)), bf16_rn(v.y - bf16_f(h1)),
                      bf16_rn(v.z - bf16_f(h2)), bf16_rn(v.w - bf16_f(h3))};
        reinterpret_cast<ushort4*>(hi)[i] = hv;
        reinterpret_cast<ushort4*>(lo)[i] = lv;
    }
}

// ------------------- split-bf16 MFMA GEMM:  C = A @ B^T --------------------
// C[z][m][n] = act( scale * sum_k A[z][m][k]*B[z][n][k] + bias[n] )
// A,B given as hi/lo bf16 planes. OUT: 0 = f32, 1 = split planes, 2 = both.
// BM=128, BN=64, BK=32; 256 threads = 4 waves (2x2 of 64x32 tiles).
// Requires M%128==0, N%64==0, K%32==0 (all shapes here satisfy this).
template<int ACT, int OUT>
__global__ __launch_bounds__(256)
void gemm_bs(const u16* __restrict__ Ah, const u16* __restrict__ Al,
             int lda, long long sA,
             const u16* __restrict__ Bh, const u16* __restrict__ Bl,
             int ldb, long long sB,
             const float* __restrict__ bias, float scale,
             float* __restrict__ Cf, u16* __restrict__ Ch, u16* __restrict__ Cl,
             int ldc, long long sC, int K)
{
    __shared__ u16 Ash[128][40];   // +8 pad: 80B row stride -> 2-way-max conflicts
    __shared__ u16 Asl[128][40];
    __shared__ u16 Bsh[64][40];
    __shared__ u16 Bsl[64][40];

    const long long zA = (long long)blockIdx.z * sA;
    const long long zB = (long long)blockIdx.z * sB;
    const long long zC = (long long)blockIdx.z * sC;
    const int m0 = blockIdx.x * 128;
    const int n0 = blockIdx.y * 64;
    const int t  = threadIdx.x;
    const int r  = t >> 2;            // 0..63 staging row
    const int ck = (t & 3) << 3;      // k-chunk of 8 bf16 (16B)
    const int lane = t & 63;
    const int wid  = t >> 6;
    const int wr = (wid >> 1) * 64;   // wave m-offset
    const int wc = (wid & 1) * 32;    // wave n-offset
    const int lr = lane & 15;
    const int lk = (lane >> 4) << 3;  // k-offset of this lane's 8 elements

    f32x4 acc[4][2];
    const f32x4 zero = {0.f, 0.f, 0.f, 0.f};
    #pragma unroll
    for (int i = 0; i < 4; ++i)
        #pragma unroll
        for (int j = 0; j < 2; ++j) acc[i][j] = zero;

    const long long arow0 = zA + (long long)(m0 + r) * lda;
    const long long arow1 = zA + (long long)(m0 + r + 64) * lda;
    const long long brow  = zB + (long long)(n0 + r) * ldb;

    for (int k0 = 0; k0 < K; k0 += 32) {
        int4 vah0 = *reinterpret_cast<const int4*>(Ah + arow0 + k0 + ck);
        int4 vah1 = *reinterpret_cast<const int4*>(Ah + arow1 + k0 + ck);
        int4 val0 = *reinterpret_cast<const int4*>(Al + arow0 + k0 + ck);
        int4 val1 = *reinterpret_cast<const int4*>(Al + arow1 + k0 + ck);
        int4 vbh  = *reinterpret_cast<const int4*>(Bh + brow  + k0 + ck);
        int4 vbl  = *reinterpret_cast<const int4*>(Bl + brow  + k0 + ck);
        __syncthreads();   // previous iter's frag reads done before overwrite
        *reinterpret_cast<int4*>(&Ash[r][ck])      = vah0;
        *reinterpret_cast<int4*>(&Ash[r + 64][ck]) = vah1;
        *reinterpret_cast<int4*>(&Asl[r][ck])      = val0;
        *reinterpret_cast<int4*>(&Asl[r + 64][ck]) = val1;
        *reinterpret_cast<int4*>(&Bsh[r][ck])      = vbh;
        *reinterpret_cast<int4*>(&Bsl[r][ck])      = vbl;
        __syncthreads();

        short8 fah[4], fal[4], fbh[2], fbl[2];
        #pragma unroll
        for (int i = 0; i < 4; ++i) {
            fah[i] = *reinterpret_cast<const short8*>(&Ash[wr + i * 16 + lr][lk]);
            fal[i] = *reinterpret_cast<const short8*>(&Asl[wr + i * 16 + lr][lk]);
        }
        #pragma unroll
        for (int j = 0; j < 2; ++j) {
            fbh[j] = *reinterpret_cast<const short8*>(&Bsh[wc + j * 16 + lr][lk]);
            fbl[j] = *reinterpret_cast<const short8*>(&Bsl[wc + j * 16 + lr][lk]);
        }
        #pragma unroll
        for (int i = 0; i < 4; ++i)
            #pragma unroll
            for (int j = 0; j < 2; ++j) {
                acc[i][j] = __builtin_amdgcn_mfma_f32_16x16x32_bf16(fah[i], fbh[j], acc[i][j], 0, 0, 0);
                acc[i][j] = __builtin_amdgcn_mfma_f32_16x16x32_bf16(fah[i], fbl[j], acc[i][j], 0, 0, 0);
                acc[i][j] = __builtin_amdgcn_mfma_f32_16x16x32_bf16(fal[i], fbh[j], acc[i][j], 0, 0, 0);
            }
    }

    // epilogue: D layout col = lane&15, row = (lane>>4)*4 + q  [m89-verified]
    #pragma unroll
    for (int j = 0; j < 2; ++j) {
        const int col = n0 + wc + j * 16 + lr;
        const float bv = bias ? bias[col] : 0.f;
        #pragma unroll
        for (int i = 0; i < 4; ++i) {
            #pragma unroll
            for (int q = 0; q < 4; ++q) {
                const int row = m0 + wr + i * 16 + ((lane >> 4) << 2) + q;
                float v = acc[i][j][q] * scale + bv;
                if (ACT) v = tanhf(v);
                const long long off = zC + (long long)row * ldc + col;
                if (OUT == 0 || OUT == 2) Cf[off] = v;
                if (OUT >= 1) {
                    u16 h = bf16_rn(v);
                    Ch[off] = h;
                    Cl[off] = bf16_rn(v - bf16_f(h));
                }
            }
        }
    }
}

// ---------- softmax over rows of 256, emits split bf16 prob planes ---------
__global__ __launch_bounds__(256)
void softmax256_split(const float* __restrict__ S, u16* __restrict__ Ph,
                      u16* __restrict__ Pl, int nrows)
{
    int wave = threadIdx.x >> 6;
    int lane = threadIdx.x & 63;
    long long row = (long long)blockIdx.x * 4 + wave;
    if (row >= nrows) return;
    float4 v = *(reinterpret_cast<const float4*>(S + row * 256) + lane);
    float mx = fmaxf(fmaxf(v.x, v.y), fmaxf(v.z, v.w));
    #pragma unroll
    for (int off = 32; off > 0; off >>= 1) mx = fmaxf(mx, __shfl_xor(mx, off, 64));
    v.x = expf(v.x - mx); v.y = expf(v.y - mx);
    v.z = expf(v.z - mx); v.w = expf(v.w - mx);
    float sm = v.x + v.y + v.z + v.w;
    #pragma unroll
    for (int off = 32; off > 0; off >>= 1) sm += __shfl_xor(sm, off, 64);
    float inv = 1.0f / sm;
    v.x *= inv; v.y *= inv; v.z *= inv; v.w *= inv;
    u16 h0 = bf16_rn(v.x), h1 = bf16_rn(v.y), h2 = bf16_rn(v.z), h3 = bf16_rn(v.w);
    ushort4 hv = {h0, h1, h2, h3};
    ushort4 lv = {bf16_rn(v.x - bf16_f(h0)), bf16_rn(v.y - bf16_f(h1)),
                  bf16_rn(v.z - bf16_f(h2)), bf16_rn(v.w - bf16_f(h3))};
    *reinterpret_cast<ushort4*>(Ph + row * 256 + lane * 4) = hv;
    *reinterpret_cast<ushort4*>(Pl + row * 256 + lane * 4) = lv;
}

// vpT[h][d][m] = kv[m][512 + h*64 + d], on both planes
__global__ __launch_bounds__(256)
void transpose_vp2(const u16* __restrict__ kvh, const u16* __restrict__ kvl,
                   u16* __restrict__ vpTh, u16* __restrict__ vpTl)
{
    int idx = blockIdx.x * 256 + threadIdx.x;   // 8*64*256 = 131072
    int m = idx & 255;
    int rest = idx >> 8;
    int d = rest & 63;
    int h = rest >> 6;
    int src = m * 1024 + 512 + h * 64 + d;
    vpTh[idx] = kvh[src];
    vpTl[idx] = kvl[src];
}

// cbar[b][h*64+d] = (1/8) sum_q ctx1[h][b*8+q][d]  -> split planes
__global__ __launch_bounds__(256)
void mean_ctx_split(const float* __restrict__ ctx1, u16* __restrict__ ch,
                    u16* __restrict__ cl)
{
    int idx = blockIdx.x * 256 + threadIdx.x;   // 2048*512
    int e = idx & 511, b = idx >> 9;
    int h = e >> 6, d = e & 63;
    const float* p = ctx1 + (long long)h * 1048576 + (long long)b * 512 + d;
    float s = 0.f;
    #pragma unroll
    for (int q = 0; q < 8; ++q) s += p[q * 64];
    float v = s * 0.125f;
    u16 hh = bf16_rn(v);
    ch[idx] = hh;
    cl[idx] = bf16_rn(v - bf16_f(hh));
}

// ctx2[b][h*64+d] = ctx2h[h][b][d] + uv[b][h*64+d]  -> split planes
__global__ __launch_bounds__(256)
void combine_ctx2_split(const float* __restrict__ c2hf, const float* __restrict__ uv,
                        u16* __restrict__ oh, u16* __restrict__ ol)
{
    int idx = blockIdx.x * 256 + threadIdx.x;   // 2048*512
    int e = idx & 511, b = idx >> 9;
    int h = e >> 6, d = e & 63;
    float v = c2hf[(long long)h * 131072 + b * 64 + d] + uv[idx];
    u16 hh = bf16_rn(v);
    oh[idx] = hh;
    ol[idx] = bf16_rn(v - bf16_f(hh));
}

// out1[b][m][e] = memory[m][e] + u[b][e]
__global__ __launch_bounds__(256)
void write_out1(const float* __restrict__ mem, const float* __restrict__ u,
                float* __restrict__ out1)
{
    const float4* m4 = reinterpret_cast<const float4*>(mem);
    const float4* u4 = reinterpret_cast<const float4*>(u);
    float4* o4 = reinterpret_cast<float4*>(out1);
    const long long total = 2048LL * 256 * 128;
    for (long long i = (long long)blockIdx.x * 256 + threadIdx.x; i < total;
         i += (long long)gridDim.x * 256) {
        int e4 = (int)(i & 127);
        int m  = (int)((i >> 7) & 255);
        long long b = i >> 15;
        float4 a = m4[m * 128 + e4];
        float4 c = u4[b * 128 + e4];
        float4 rr = {a.x + c.x, a.y + c.y, a.z + c.z, a.w + c.w};
        o4[i] = rr;
    }
}

extern "C" void kernel_launch(void* const* d_in, const int* in_sizes, int n_in,
                              void* d_out, int out_size, void* d_ws, size_t ws_size,
                              hipStream_t stream)
{
    (void)in_sizes; (void)n_in; (void)out_size; (void)ws_size;
    const float* x     = (const float*)d_in[0];
    const float* mem   = (const float*)d_in[1];
    const float* enc_w = (const float*)d_in[2];
    const float* enc_b = (const float*)d_in[3];
    const float* blk_w = (const float*)d_in[4];
    const float* blk_b = (const float*)d_in[5];
    const float* in_w  = (const float*)d_in[6];
    const float* in_b  = (const float*)d_in[7];
    const float* out_w = (const float*)d_in[8];
    const float* out_b = (const float*)d_in[9];
    const float* dec_w = (const float*)d_in[10];
    const float* dec_b = (const float*)d_in[11];
    float* out = (float*)d_out;

    // ---------------- workspace carve-up (all 256B-aligned) ----------------
    char* p = (char*)d_ws;
    auto alloc = [&](size_t bytes) { char* q = p; p += (bytes + 255) & ~(size_t)255; return q; };
    u16* xh    = (u16*)alloc(2097152 * 2); u16* xl    = (u16*)alloc(2097152 * 2);
    u16* memh  = (u16*)alloc(131072 * 2);  u16* meml  = (u16*)alloc(131072 * 2);
    u16* ewh   = (u16*)alloc(524288 * 2);  u16* ewl   = (u16*)alloc(524288 * 2);
    u16* bwh   = (u16*)alloc(2097152 * 2); u16* bwl   = (u16*)alloc(2097152 * 2);
    u16* iwh   = (u16*)alloc(786432 * 2);  u16* iwl   = (u16*)alloc(786432 * 2);
    u16* owh   = (u16*)alloc(262144 * 2);  u16* owl   = (u16*)alloc(262144 * 2);
    u16* dwh   = (u16*)alloc(524288 * 2);  u16* dwl   = (u16*)alloc(524288 * 2);
    u16* ench  = (u16*)alloc(1048576 * 2); u16* encl  = (u16*)alloc(1048576 * 2);
    u16* kvh   = (u16*)alloc(262144 * 2);  u16* kvl   = (u16*)alloc(262144 * 2);
    u16* vpTh  = (u16*)alloc(131072 * 2);  u16* vpTl  = (u16*)alloc(131072 * 2);
    u16* cbh   = (u16*)alloc(1048576 * 2); u16* cbl   = (u16*)alloc(1048576 * 2);
    float* uf  = (float*)alloc(1048576 * 4);
    u16* uh    = (u16*)alloc(1048576 * 2); u16* ul    = (u16*)alloc(1048576 * 2);
    u16* qp2h  = (u16*)alloc(1048576 * 2); u16* qp2l  = (u16*)alloc(1048576 * 2);
    float* uvb = (float*)alloc(1048576 * 4);
    float* c2hf= (float*)alloc(1048576 * 4);
    u16* c2h   = (u16*)alloc(1048576 * 2); u16* c2l   = (u16*)alloc(1048576 * 2);
    u16* reth  = (u16*)alloc(1048576 * 2); u16* retl  = (u16*)alloc(1048576 * 2);

    // ------- scratch inside the not-yet-written updated_memory region ------
    float* out1 = out + 2097152;                      // 268,435,456 floats
    float* S1   = out1;                               // 33,554,432 f (134 MB)
    u16*  Ph    = (u16*)(out1 + 33554432);            // 33,554,432 u16
    u16*  Pl    = Ph + 33554432;
    float* S2   = (float*)(Pl + 33554432);            // 4,194,304 f
    u16*  P2h   = (u16*)(S2 + 4194304);               // 4,194,304 u16
    u16*  P2l   = P2h + 4194304;
    float* ctx1f= (float*)(P2l + 4194304);            // 8,388,608 f
    u16*  muh   = (u16*)(ctx1f + 8388608);            // 8,388,608 u16
    u16*  mul   = muh + 8388608;
    u16*  qp1h  = mul + 8388608;
    u16*  qp1l  = qp1h + 8388608;                     // total ~403 MB < 1073 MB

    dim3 blk(256);

    // 0. split conversions of f32 inputs
    split_f32<<<dim3(2048), blk, 0, stream>>>(x,     xh,  xl,  524288);
    split_f32<<<dim3(128),  blk, 0, stream>>>(mem,   memh,meml, 32768);
    split_f32<<<dim3(512),  blk, 0, stream>>>(enc_w, ewh, ewl, 131072);
    split_f32<<<dim3(2048), blk, 0, stream>>>(blk_w, bwh, bwl, 524288);
    split_f32<<<dim3(768),  blk, 0, stream>>>(in_w,  iwh, iwl, 196608);
    split_f32<<<dim3(256),  blk, 0, stream>>>(out_w, owh, owl, 65536);
    split_f32<<<dim3(512),  blk, 0, stream>>>(dec_w, dwh, dwl, 131072);

    // 1. encoded = tanh(x @ enc_w^T + enc_b)    M=2048 N=512 K=1024
    gemm_bs<1,1><<<dim3(16, 8, 1), blk, 0, stream>>>(xh, xl, 1024, 0, ewh, ewl, 1024, 0,
        enc_b, 1.0f, nullptr, ench, encl, 512, 0, 1024);
    // 2. mu = encoded @ blk_w^T + blk_b         M=2048 N=4096 K=512
    gemm_bs<0,1><<<dim3(16, 64, 1), blk, 0, stream>>>(ench, encl, 512, 0, bwh, bwl, 512, 0,
        blk_b, 1.0f, nullptr, muh, mul, 4096, 0, 512);
    // 3. qp1 = mu(16384x512) @ wq^T + bq        M=16384 N=512 K=512
    gemm_bs<0,1><<<dim3(128, 8, 1), blk, 0, stream>>>(muh, mul, 512, 0, iwh, iwl, 512, 0,
        in_b, 1.0f, nullptr, qp1h, qp1l, 512, 0, 512);
    // 4. kv = memory @ [wk|wv]^T + [bk|bv]      M=256 N=1024 K=512
    gemm_bs<0,1><<<dim3(2, 16, 1), blk, 0, stream>>>(memh, meml, 512, 0,
        iwh + 512 * 512, iwl + 512 * 512, 512, 0,
        in_b + 512, 1.0f, nullptr, kvh, kvl, 1024, 0, 512);
    // 5. vpT planes
    transpose_vp2<<<dim3(512), blk, 0, stream>>>(kvh, kvl, vpTh, vpTl);
    // 6. scores1[h] = 0.125 * qp1_h @ kp_h^T    M=16384 N=256 K=64, z=8
    gemm_bs<0,0><<<dim3(128, 4, 8), blk, 0, stream>>>(qp1h, qp1l, 512, 64, kvh, kvl, 1024, 64,
        nullptr, 0.125f, S1, nullptr, nullptr, 256, 16384LL * 256, 64);
    // 7. softmax -> split prob planes
    softmax256_split<<<dim3(32768), blk, 0, stream>>>(S1, Ph, Pl, 131072);
    // 8. ctx1[h] = attn_h @ vpT_h^T             M=16384 N=64 K=256, z=8
    gemm_bs<0,0><<<dim3(128, 1, 8), blk, 0, stream>>>(Ph, Pl, 256, 16384LL * 256,
        vpTh, vpTl, 256, 16384, nullptr, 1.0f, ctx1f, nullptr, nullptr, 64, 16384LL * 64, 256);
    // 9. cbar = mean_q ctx1  -> split
    mean_ctx_split<<<dim3(4096), blk, 0, stream>>>(ctx1f, cbh, cbl);
    // 10. u = cbar @ out_w^T + out_b  (f32 + split)   M=2048 N=512 K=512
    gemm_bs<0,2><<<dim3(16, 8, 1), blk, 0, stream>>>(cbh, cbl, 512, 0, owh, owl, 512, 0,
        out_b, 1.0f, uf, uh, ul, 512, 0, 512);
    // 11. qp2 = encoded @ wq^T + bq             M=2048 N=512 K=512
    gemm_bs<0,1><<<dim3(16, 8, 1), blk, 0, stream>>>(ench, encl, 512, 0, iwh, iwl, 512, 0,
        in_b, 1.0f, nullptr, qp2h, qp2l, 512, 0, 512);
    // 12. uvb = u @ wv^T (bv already in vp)      M=2048 N=512 K=512
    gemm_bs<0,0><<<dim3(16, 8, 1), blk, 0, stream>>>(uh, ul, 512, 0,
        iwh + 1024 * 512, iwl + 1024 * 512, 512, 0,
        nullptr, 1.0f, uvb, nullptr, nullptr, 512, 0, 512);
    // 13. scores2[h] = 0.125 * qp2_h @ kp_h^T   M=2048 N=256 K=64, z=8
    gemm_bs<0,0><<<dim3(16, 4, 8), blk, 0, stream>>>(qp2h, qp2l, 512, 64, kvh, kvl, 1024, 64,
        nullptr, 0.125f, S2, nullptr, nullptr, 256, 2048LL * 256, 64);
    // 14. softmax2 -> split
    softmax256_split<<<dim3(4096), blk, 0, stream>>>(S2, P2h, P2l, 16384);
    // 15. ctx2h[h] = attn2_h @ vpT_h^T          M=2048 N=64 K=256, z=8
    gemm_bs<0,0><<<dim3(16, 1, 8), blk, 0, stream>>>(P2h, P2l, 256, 2048LL * 256,
        vpTh, vpTl, 256, 16384, nullptr, 1.0f, c2hf, nullptr, nullptr, 64, 2048LL * 64, 256);
    // 16. updated_memory (overwrites all out1-region scratch; last reader was 15)
    write_out1<<<dim3(4096), blk, 0, stream>>>(mem, uf, out1);
    // 17. ctx2 = ctx2h + uv -> split
    combine_ctx2_split<<<dim3(4096), blk, 0, stream>>>(c2hf, uvb, c2h, c2l);
    // 18. retrieved = ctx2 @ out_w^T + out_b    M=2048 N=512 K=512
    gemm_bs<0,1><<<dim3(16, 8, 1), blk, 0, stream>>>(c2h, c2l, 512, 0, owh, owl, 512, 0,
        out_b, 1.0f, nullptr, reth, retl, 512, 0, 512);
    // 19. output = retrieved @ dec_w^T + dec_b  M=2048 N=1024 K=512
    gemm_bs<0,0><<<dim3(16, 16, 1), blk, 0, stream>>>(reth, retl, 512, 0, dwh, dwl, 512, 0,
        dec_b, 1.0f, out, nullptr, nullptr, 1024, 0, 512);
}

// Round 3
// 685.998 us; speedup vs baseline: 1.6245x; 1.0816x over previous
//
#include <hip/hip_runtime.h>
#include <math.h>

// ---------------------------------------------------------------------------
// MemoryAugmentedNetwork — split-bf16 MFMA + fused attention + weight folding
// Shapes: B=2048, IN=1024, E=512, M=256, NB=H=8, D=64
// Exact algebra: MHA1 K/V shared (memory broadcast); u = mean(ctx)@out_w^T;
// MHA2's (memory+u) K/V collapse (uk const in softmax; sum attn = 1);
// NEW R3: qp1 = enc @ W1[n]^T + bias1[n],  W1[n] = wq@blk_w[n]  (mu never built)
//         output = ctx2 @ W2^T + bias2,    W2    = dec_w@out_w  (retr never built)
//         MHA1: scores+softmax+PV+q-mean fused in one kernel (S never in HBM)
//         MHA2: same fusion + "+uv" epilogue.
// Precision: every GEMM/attn product uses split bf16 (a=ah+al),
// C = Ah*Bh + Ah*Bl + Al*Bh, f32 accum -> ~2^-18 relative input error.
// ---------------------------------------------------------------------------

typedef __attribute__((ext_vector_type(8))) short short8;
typedef __attribute__((ext_vector_type(4))) float f32x4;
typedef unsigned short u16;

__device__ inline u16 bf16_rn(float x) {
    unsigned u = __float_as_uint(x);
    unsigned r = (u + 0x7FFFu + ((u >> 16) & 1u)) >> 16;
    return (u16)r;
}
__device__ inline float bf16_f(u16 h) { return __uint_as_float(((unsigned)h) << 16); }

// ---------------- f32 -> (hi, lo) bf16 planes, vectorized ------------------
__global__ __launch_bounds__(256)
void split_f32(const float* __restrict__ in, u16* __restrict__ hi,
               u16* __restrict__ lo, long long n4)
{
    for (long long i = (long long)blockIdx.x * 256 + threadIdx.x; i < n4;
         i += (long long)gridDim.x * 256) {
        float4 v = reinterpret_cast<const float4*>(in)[i];
        u16 h0 = bf16_rn(v.x), h1 = bf16_rn(v.y), h2 = bf16_rn(v.z), h3 = bf16_rn(v.w);
        ushort4 hv = {h0, h1, h2, h3};
        ushort4 lv = {bf16_rn(v.x - bf16_f(h0)), bf16_rn(v.y - bf16_f(h1)),
                      bf16_rn(v.z - bf16_f(h2)), bf16_rn(v.w - bf16_f(h3))};
        reinterpret_cast<ushort4*>(hi)[i] = hv;
        reinterpret_cast<ushort4*>(lo)[i] = lv;
    }
}

// ---- transpose + split: src f32 [z][R][C] -> dst planes [z][C][R] ---------
__global__ __launch_bounds__(256)
void tr_split(const float* __restrict__ src, u16* __restrict__ dh,
              u16* __restrict__ dl, int R, int C)
{
    __shared__ float T[32][33];
    const int z = blockIdx.z;
    const int c0 = blockIdx.x * 32, r0 = blockIdx.y * 32;
    const int tx = threadIdx.x & 31, ty = threadIdx.x >> 5;
    const float* s = src + (long long)z * R * C;
    #pragma unroll
    for (int rr = 0; rr < 4; ++rr)
        T[ty + rr * 8][tx] = s[(long long)(r0 + ty + rr * 8) * C + c0 + tx];
    __syncthreads();
    #pragma unroll
    for (int rr = 0; rr < 4; ++rr) {
        float v = T[tx][ty + rr * 8];
        long long o = (long long)z * R * C + (long long)(c0 + ty + rr * 8) * R + r0 + tx;
        u16 hh = bf16_rn(v);
        dh[o] = hh; dl[o] = bf16_rn(v - bf16_f(hh));
    }
}

// bias1[n][f] = sum_o wq[f,o]*blk_b[n,o] + bq[f]     (4096 outputs)
__global__ __launch_bounds__(256)
void bias1_k(const float* __restrict__ wq, const float* __restrict__ blk_b,
             const float* __restrict__ bq, float* __restrict__ bias1)
{
    int idx = blockIdx.x * 256 + threadIdx.x;   // 8*512
    int n = idx >> 9, f = idx & 511;
    float s = bq[f];
    const float* wr_ = wq + f * 512;
    const float* bb = blk_b + n * 512;
    for (int o = 0; o < 512; ++o) s += wr_[o] * bb[o];
    bias1[idx] = s;
}

// bias2[i] = sum_f dec_w[i,f]*out_b[f] + dec_b[i]    (1024 outputs)
__global__ __launch_bounds__(256)
void bias2_k(const float* __restrict__ dec_w, const float* __restrict__ out_b,
             const float* __restrict__ dec_b, float* __restrict__ bias2)
{
    int i = blockIdx.x * 256 + threadIdx.x;     // 1024
    float s = dec_b[i];
    const float* dr = dec_w + i * 512;
    for (int f = 0; f < 512; ++f) s += dr[f] * out_b[f];
    bias2[i] = s;
}

// ------------------- split-bf16 MFMA GEMM:  C = A @ B^T --------------------
// C[z][m][n] = act( (sum_k A*B + bias[z*bstride + n]) * scale )
// OUT: 0 = f32, 1 = split planes, 2 = both.  BM=128,BN=64,BK=32, 4 waves.
template<int ACT, int OUT>
__global__ __launch_bounds__(256)
void gemm_bs(const u16* __restrict__ Ah, const u16* __restrict__ Al,
             int lda, long long sA,
             const u16* __restrict__ Bh, const u16* __restrict__ Bl,
             int ldb, long long sB,
             const float* __restrict__ bias, long long bstride, float scale,
             float* __restrict__ Cf, u16* __restrict__ Ch, u16* __restrict__ Cl,
             int ldc, long long sC, int K)
{
    __shared__ u16 Ash[128][40];
    __shared__ u16 Asl[128][40];
    __shared__ u16 Bsh[64][40];
    __shared__ u16 Bsl[64][40];

    const long long zA = (long long)blockIdx.z * sA;
    const long long zB = (long long)blockIdx.z * sB;
    const long long zC = (long long)blockIdx.z * sC;
    const int m0 = blockIdx.x * 128;
    const int n0 = blockIdx.y * 64;
    const int t  = threadIdx.x;
    const int r  = t >> 2;
    const int ck = (t & 3) << 3;
    const int lane = t & 63;
    const int wid  = t >> 6;
    const int wr = (wid >> 1) * 64;
    const int wc = (wid & 1) * 32;
    const int lr = lane & 15;
    const int lk = (lane >> 4) << 3;

    f32x4 acc[4][2];
    const f32x4 zero = {0.f, 0.f, 0.f, 0.f};
    #pragma unroll
    for (int i = 0; i < 4; ++i)
        #pragma unroll
        for (int j = 0; j < 2; ++j) acc[i][j] = zero;

    const long long arow0 = zA + (long long)(m0 + r) * lda;
    const long long arow1 = zA + (long long)(m0 + r + 64) * lda;
    const long long brow  = zB + (long long)(n0 + r) * ldb;

    for (int k0 = 0; k0 < K; k0 += 32) {
        int4 vah0 = *reinterpret_cast<const int4*>(Ah + arow0 + k0 + ck);
        int4 vah1 = *reinterpret_cast<const int4*>(Ah + arow1 + k0 + ck);
        int4 val0 = *reinterpret_cast<const int4*>(Al + arow0 + k0 + ck);
        int4 val1 = *reinterpret_cast<const int4*>(Al + arow1 + k0 + ck);
        int4 vbh  = *reinterpret_cast<const int4*>(Bh + brow  + k0 + ck);
        int4 vbl  = *reinterpret_cast<const int4*>(Bl + brow  + k0 + ck);
        __syncthreads();
        *reinterpret_cast<int4*>(&Ash[r][ck])      = vah0;
        *reinterpret_cast<int4*>(&Ash[r + 64][ck]) = vah1;
        *reinterpret_cast<int4*>(&Asl[r][ck])      = val0;
        *reinterpret_cast<int4*>(&Asl[r + 64][ck]) = val1;
        *reinterpret_cast<int4*>(&Bsh[r][ck])      = vbh;
        *reinterpret_cast<int4*>(&Bsl[r][ck])      = vbl;
        __syncthreads();

        short8 fah[4], fal[4], fbh[2], fbl[2];
        #pragma unroll
        for (int i = 0; i < 4; ++i) {
            fah[i] = *reinterpret_cast<const short8*>(&Ash[wr + i * 16 + lr][lk]);
            fal[i] = *reinterpret_cast<const short8*>(&Asl[wr + i * 16 + lr][lk]);
        }
        #pragma unroll
        for (int j = 0; j < 2; ++j) {
            fbh[j] = *reinterpret_cast<const short8*>(&Bsh[wc + j * 16 + lr][lk]);
            fbl[j] = *reinterpret_cast<const short8*>(&Bsl[wc + j * 16 + lr][lk]);
        }
        #pragma unroll
        for (int i = 0; i < 4; ++i)
            #pragma unroll
            for (int j = 0; j < 2; ++j) {
                acc[i][j] = __builtin_amdgcn_mfma_f32_16x16x32_bf16(fah[i], fbh[j], acc[i][j], 0, 0, 0);
                acc[i][j] = __builtin_amdgcn_mfma_f32_16x16x32_bf16(fah[i], fbl[j], acc[i][j], 0, 0, 0);
                acc[i][j] = __builtin_amdgcn_mfma_f32_16x16x32_bf16(fal[i], fbh[j], acc[i][j], 0, 0, 0);
            }
    }

    #pragma unroll
    for (int j = 0; j < 2; ++j) {
        const int col = n0 + wc + j * 16 + lr;
        const float bv = bias ? bias[blockIdx.z * bstride + col] : 0.f;
        #pragma unroll
        for (int i = 0; i < 4; ++i) {
            #pragma unroll
            for (int q = 0; q < 4; ++q) {
                const int row = m0 + wr + i * 16 + ((lane >> 4) << 2) + q;
                float v = (acc[i][j][q] + bv) * scale;
                if (ACT) v = tanhf(v);
                const long long off = zC + (long long)row * ldc + col;
                if (OUT == 0 || OUT == 2) Cf[off] = v;
                if (OUT >= 1) {
                    u16 h = bf16_rn(v);
                    Ch[off] = h;
                    Cl[off] = bf16_rn(v - bf16_f(h));
                }
            }
        }
    }
}

// vpT[h][d][m] = kv[m][512 + h*64 + d], both planes
__global__ __launch_bounds__(256)
void transpose_vp2(const u16* __restrict__ kvh, const u16* __restrict__ kvl,
                   u16* __restrict__ vpTh, u16* __restrict__ vpTl)
{
    int idx = blockIdx.x * 256 + threadIdx.x;   // 131072
    int m = idx & 255;
    int rest = idx >> 8;
    int d = rest & 63;
    int h = rest >> 6;
    int src = m * 1024 + 512 + h * 64 + d;
    vpTh[idx] = kvh[src];
    vpTl[idx] = kvl[src];
}

// ------------------------- fused attention ---------------------------------
// 128 q-rows x 256 keys x 64 d per block; 4 waves; Q,K staged in LDS;
// S (pre-scaled by 0.125 via qp) in registers; split-bf16 P -> LDS (XOR swz,
// col-halved); V^T staged per half; PV accumulates; softmax norm deferred.
// MODE 0: Q = qp1 [q][2048][512] h-slice, rows = q*16+bb (16 batches),
//         epilogue = q-mean*(1/8) -> cbar split planes.
// MODE 1: Q = qp2 [2048][512], rows = batches, epilogue = +uv -> c2 planes.
template<int MODE>
__global__ __launch_bounds__(256, 1)
void fused_attn(const u16* __restrict__ Qph, const u16* __restrict__ Qpl,
                const u16* __restrict__ Kvh, const u16* __restrict__ Kvl,
                const u16* __restrict__ VTh, const u16* __restrict__ VTl,
                const float* __restrict__ uv,
                u16* __restrict__ Oh, u16* __restrict__ Ol)
{
    extern __shared__ char smem[];   // 110592 B
    const int h = blockIdx.y;
    const int t = threadIdx.x;
    const int lane = t & 63, w = t >> 6;
    const int l15 = lane & 15, g = lane >> 4;
    const int wr = w * 32;
    const int b0 = blockIdx.x * (MODE == 0 ? 16 : 128);

    u16* Qs = (u16*)smem;                 // [2][128][72] u16 -> 36864 B
    u16* Ks = (u16*)(smem + 36864);       // [2][256][72] u16 -> 73728 B

    // ---- stage Q (128 rows x 64 u16 x 2 planes = 2048 x 16B) ----
    for (int c = t; c < 2048; c += 256) {
        int plane = c >> 10, rem = c & 1023;
        int row = rem >> 3, seg = rem & 7;
        const u16* src = plane ? Qpl : Qph;
        long long addr;
        if (MODE == 0) {
            int q = row >> 4, bb = row & 15;
            addr = ((long long)q * 2048 + b0 + bb) * 512 + h * 64 + seg * 8;
        } else {
            addr = (long long)(b0 + row) * 512 + h * 64 + seg * 8;
        }
        *(int4*)(&Qs[plane * 9216 + row * 72 + seg * 8]) = *(const int4*)(src + addr);
    }
    // ---- stage K (256 rows) ----
    for (int c = t; c < 4096; c += 256) {
        int plane = c >> 11, rem = c & 2047;
        int row = rem >> 3, seg = rem & 7;
        const u16* src = plane ? Kvl : Kvh;
        *(int4*)(&Ks[plane * 18432 + row * 72 + seg * 8]) =
            *(const int4*)(src + (long long)row * 1024 + h * 64 + seg * 8);
    }
    __syncthreads();

    // ---- S = Q @ K^T  (rows: wave-local 32; cols: 256 keys) ----
    f32x4 sacc[2][16];
    const f32x4 zero = {0.f, 0.f, 0.f, 0.f};
    #pragma unroll
    for (int i = 0; i < 2; ++i)
        #pragma unroll
        for (int j = 0; j < 16; ++j) sacc[i][j] = zero;

    short8 qfh[2][2], qfl[2][2];
    #pragma unroll
    for (int i = 0; i < 2; ++i)
        #pragma unroll
        for (int kf = 0; kf < 2; ++kf) {
            int ro = (wr + 16 * i + l15) * 72 + kf * 32 + g * 8;
            qfh[i][kf] = *(const short8*)(&Qs[ro]);
            qfl[i][kf] = *(const short8*)(&Qs[9216 + ro]);
        }
    #pragma unroll
    for (int j = 0; j < 16; ++j) {
        #pragma unroll
        for (int kf = 0; kf < 2; ++kf) {
            int ro = (16 * j + l15) * 72 + kf * 32 + g * 8;
            short8 kbh = *(const short8*)(&Ks[ro]);
            short8 kbl = *(const short8*)(&Ks[18432 + ro]);
            #pragma unroll
            for (int i = 0; i < 2; ++i) {
                sacc[i][j] = __builtin_amdgcn_mfma_f32_16x16x32_bf16(qfh[i][kf], kbh, sacc[i][j], 0, 0, 0);
                sacc[i][j] = __builtin_amdgcn_mfma_f32_16x16x32_bf16(qfh[i][kf], kbl, sacc[i][j], 0, 0, 0);
                sacc[i][j] = __builtin_amdgcn_mfma_f32_16x16x32_bf16(qfl[i][kf], kbh, sacc[i][j], 0, 0, 0);
            }
        }
    }

    // ---- softmax (rows live on (g,q); reduce across l15 group) ----
    float mx[2][4], inv[2][4];
    #pragma unroll
    for (int i = 0; i < 2; ++i)
        #pragma unroll
        for (int q = 0; q < 4; ++q) {
            float m = -1e30f;
            #pragma unroll
            for (int j = 0; j < 16; ++j) m = fmaxf(m, sacc[i][j][q]);
            #pragma unroll
            for (int off = 1; off <= 8; off <<= 1) m = fmaxf(m, __shfl_xor(m, off, 64));
            mx[i][q] = m;
        }
    #pragma unroll
    for (int i = 0; i < 2; ++i)
        #pragma unroll
        for (int j = 0; j < 16; ++j)
            #pragma unroll
            for (int q = 0; q < 4; ++q)
                sacc[i][j][q] = __expf(sacc[i][j][q] - mx[i][q]);
    #pragma unroll
    for (int i = 0; i < 2; ++i)
        #pragma unroll
        for (int q = 0; q < 4; ++q) {
            float s = 0.f;
            #pragma unroll
            for (int j = 0; j < 16; ++j) s += sacc[i][j][q];
            #pragma unroll
            for (int off = 1; off <= 8; off <<= 1) s += __shfl_xor(s, off, 64);
            inv[i][q] = 1.0f / s;
        }

    // ---- PV in two key-halves; P,V^T in LDS (XOR swizzle) ----
    f32x4 ctx[2][4];
    #pragma unroll
    for (int i = 0; i < 2; ++i)
        #pragma unroll
        for (int jd = 0; jd < 4; ++jd) ctx[i][jd] = zero;

    for (int half = 0; half < 2; ++half) {
        __syncthreads();   // all waves done reading Q/K (or prev P/VT)
        // write split P for keys [half*128, half*128+128)
        #pragma unroll
        for (int i = 0; i < 2; ++i)
            #pragma unroll
            for (int jj = 0; jj < 8; ++jj) {
                int j = half * 8 + jj;
                #pragma unroll
                for (int q = 0; q < 4; ++q) {
                    int row = wr + 16 * i + 4 * g + q;
                    int ml = jj * 16 + l15;
                    float p = sacc[i][j][q];
                    u16 ph = bf16_rn(p);
                    u16 pl = bf16_rn(p - bf16_f(ph));
                    int byt = row * 256 + ((ml * 2) ^ ((row & 7) << 4));
                    *(u16*)(smem + byt) = ph;
                    *(u16*)(smem + 32768 + byt) = pl;
                }
            }
        // stage V^T half: [2][64][128] u16 swizzled at byte 65536
        for (int c = t; c < 2048; c += 256) {
            int plane = c >> 10, rem = c & 1023;
            int row = rem >> 4, seg = rem & 15;
            const u16* src = plane ? VTl : VTh;
            int4 v = *(const int4*)(src + (long long)h * 16384 + row * 256 + half * 128 + seg * 8);
            int byt = 65536 + plane * 16384 + row * 256 + ((seg * 16) ^ ((row & 7) << 4));
            *(int4*)(smem + byt) = v;
        }
        __syncthreads();

        short8 pah[2][4], pal[2][4];
        #pragma unroll
        for (int i = 0; i < 2; ++i)
            #pragma unroll
            for (int kf = 0; kf < 4; ++kf) {
                int row = wr + 16 * i + l15;
                int byt = row * 256 + (((kf * 64 + g * 16)) ^ ((row & 7) << 4));
                pah[i][kf] = *(const short8*)(smem + byt);
                pal[i][kf] = *(const short8*)(smem + 32768 + byt);
            }
        #pragma unroll
        for (int jd = 0; jd < 4; ++jd) {
            #pragma unroll
            for (int kf = 0; kf < 4; ++kf) {
                int row = 16 * jd + l15;
                int byt = 65536 + row * 256 + (((kf * 64 + g * 16)) ^ ((row & 7) << 4));
                short8 vbh = *(const short8*)(smem + byt);
                short8 vbl = *(const short8*)(smem + 16384 + byt);
                #pragma unroll
                for (int i = 0; i < 2; ++i) {
                    ctx[i][jd] = __builtin_amdgcn_mfma_f32_16x16x32_bf16(pah[i][kf], vbh, ctx[i][jd], 0, 0, 0);
                    ctx[i][jd] = __builtin_amdgcn_mfma_f32_16x16x32_bf16(pah[i][kf], vbl, ctx[i][jd], 0, 0, 0);
                    ctx[i][jd] = __builtin_amdgcn_mfma_f32_16x16x32_bf16(pal[i][kf], vbh, ctx[i][jd], 0, 0, 0);
                }
            }
        }
    }

    // ---- epilogue ----
    if (MODE == 0) {
        __syncthreads();
        float* R = (float*)smem;   // [8 q][16 b][64 d]
        #pragma unroll
        for (int i = 0; i < 2; ++i)
            #pragma unroll
            for (int jd = 0; jd < 4; ++jd)
                #pragma unroll
                for (int q = 0; q < 4; ++q) {
                    int qa = 2 * w + i;
                    int bb = 4 * g + q;
                    int d  = 16 * jd + l15;
                    R[qa * 1024 + bb * 64 + d] = ctx[i][jd][q] * inv[i][q];
                }
        __syncthreads();
        for (int o = t; o < 1024; o += 256) {
            int bb = o >> 6, d = o & 63;
            float s = 0.f;
            #pragma unroll
            for (int qa = 0; qa < 8; ++qa) s += R[qa * 1024 + bb * 64 + d];
            s *= 0.125f;
            long long addr = (long long)(b0 + bb) * 512 + h * 64 + d;
            u16 hh = bf16_rn(s);
            Oh[addr] = hh;
            Ol[addr] = bf16_rn(s - bf16_f(hh));
        }
    } else {
        #pragma unroll
        for (int i = 0; i < 2; ++i)
            #pragma unroll
            for (int jd = 0; jd < 4; ++jd)
                #pragma unroll
                for (int q = 0; q < 4; ++q) {
                    int b = b0 + wr + 16 * i + 4 * g + q;
                    int d = 16 * jd + l15;
                    long long addr = (long long)b * 512 + h * 64 + d;
                    float v = ctx[i][jd][q] * inv[i][q] + uv[addr];
                    u16 hh = bf16_rn(v);
                    Oh[addr] = hh;
                    Ol[addr] = bf16_rn(v - bf16_f(hh));
                }
    }
}

// out1[b][m][e] = memory[m][e] + u[b][e]
__global__ __launch_bounds__(256)
void write_out1(const float* __restrict__ mem, const float* __restrict__ u,
                float* __restrict__ out1)
{
    const float4* m4 = reinterpret_cast<const float4*>(mem);
    const float4* u4 = reinterpret_cast<const float4*>(u);
    float4* o4 = reinterpret_cast<float4*>(out1);
    const long long total = 2048LL * 256 * 128;
    for (long long i = (long long)blockIdx.x * 256 + threadIdx.x; i < total;
         i += (long long)gridDim.x * 256) {
        int e4 = (int)(i & 127);
        int m  = (int)((i >> 7) & 255);
        long long b = i >> 15;
        float4 a = m4[m * 128 + e4];
        float4 c = u4[b * 128 + e4];
        float4 rr = {a.x + c.x, a.y + c.y, a.z + c.z, a.w + c.w};
        o4[i] = rr;
    }
}

extern "C" void kernel_launch(void* const* d_in, const int* in_sizes, int n_in,
                              void* d_out, int out_size, void* d_ws, size_t ws_size,
                              hipStream_t stream)
{
    (void)in_sizes; (void)n_in; (void)out_size; (void)ws_size;
    const float* x     = (const float*)d_in[0];
    const float* mem   = (const float*)d_in[1];
    const float* enc_w = (const float*)d_in[2];
    const float* enc_b = (const float*)d_in[3];
    const float* blk_w = (const float*)d_in[4];
    const float* blk_b = (const float*)d_in[5];
    const float* in_w  = (const float*)d_in[6];
    const float* in_b  = (const float*)d_in[7];
    const float* out_w = (const float*)d_in[8];
    const float* out_b = (const float*)d_in[9];
    const float* dec_w = (const float*)d_in[10];
    const float* dec_b = (const float*)d_in[11];
    float* out = (float*)d_out;

    // ---------------- workspace carve-up (256B-aligned) --------------------
    char* p = (char*)d_ws;
    auto alloc = [&](size_t bytes) { char* q = p; p += (bytes + 255) & ~(size_t)255; return q; };
    u16* xh   = (u16*)alloc(2097152 * 2); u16* xl   = (u16*)alloc(2097152 * 2);
    u16* memh = (u16*)alloc(131072 * 2);  u16* meml = (u16*)alloc(131072 * 2);
    u16* ewh  = (u16*)alloc(524288 * 2);  u16* ewl  = (u16*)alloc(524288 * 2);
    u16* iwh  = (u16*)alloc(786432 * 2);  u16* iwl  = (u16*)alloc(786432 * 2);
    u16* owh  = (u16*)alloc(262144 * 2);  u16* owl  = (u16*)alloc(262144 * 2);
    u16* owTh = (u16*)alloc(262144 * 2);  u16* owTl = (u16*)alloc(262144 * 2);
    u16* dwh  = (u16*)alloc(524288 * 2);  u16* dwl  = (u16*)alloc(524288 * 2);
    u16* ench = (u16*)alloc(1048576 * 2); u16* encl = (u16*)alloc(1048576 * 2);
    u16* kvh  = (u16*)alloc(262144 * 2);  u16* kvl  = (u16*)alloc(262144 * 2);
    u16* vpTh = (u16*)alloc(131072 * 2);  u16* vpTl = (u16*)alloc(131072 * 2);
    float* bias1 = (float*)alloc(4096 * 4);
    float* bias2 = (float*)alloc(1024 * 4);
    u16* cbh  = (u16*)alloc(1048576 * 2); u16* cbl  = (u16*)alloc(1048576 * 2);
    float* uf = (float*)alloc(1048576 * 4);
    u16* uh   = (u16*)alloc(1048576 * 2); u16* ul   = (u16*)alloc(1048576 * 2);
    u16* qp2h = (u16*)alloc(1048576 * 2); u16* qp2l = (u16*)alloc(1048576 * 2);
    float* uvb = (float*)alloc(1048576 * 4);
    u16* c2h  = (u16*)alloc(1048576 * 2); u16* c2l  = (u16*)alloc(1048576 * 2);
    u16* W2h  = (u16*)alloc(524288 * 2);  u16* W2l  = (u16*)alloc(524288 * 2);

    // ------ big scratch in the not-yet-written updated_memory region -------
    float* out1 = out + 2097152;
    u16* bwTh = (u16*)out1;               // [8][512][512]
    u16* bwTl = bwTh + 2097152;
    u16* W1h  = bwTl + 2097152;           // [8][512][512]
    u16* W1l  = W1h + 2097152;
    u16* qp1h = W1l + 2097152;            // [8][2048][512]
    u16* qp1l = qp1h + 8388608;           // total ~50 MB << 1 GB

    dim3 blk(256);

    // 0. input conversions
    split_f32<<<dim3(2048), blk, 0, stream>>>(x,     xh,   xl,   524288);
    split_f32<<<dim3(128),  blk, 0, stream>>>(mem,   memh, meml, 32768);
    split_f32<<<dim3(512),  blk, 0, stream>>>(enc_w, ewh,  ewl,  131072);
    split_f32<<<dim3(768),  blk, 0, stream>>>(in_w,  iwh,  iwl,  196608);
    split_f32<<<dim3(256),  blk, 0, stream>>>(out_w, owh,  owl,  65536);
    split_f32<<<dim3(512),  blk, 0, stream>>>(dec_w, dwh,  dwl,  131072);
    tr_split<<<dim3(16, 16, 8), blk, 0, stream>>>(blk_w, bwTh, bwTl, 512, 512);
    tr_split<<<dim3(16, 16, 1), blk, 0, stream>>>(out_w, owTh, owTl, 512, 512);
    bias1_k<<<dim3(16), blk, 0, stream>>>(in_w, blk_b, in_b, bias1);
    bias2_k<<<dim3(4), blk, 0, stream>>>(dec_w, out_b, dec_b, bias2);

    // 1. encoded = tanh(x @ enc_w^T + enc_b)
    gemm_bs<1,1><<<dim3(16, 8, 1), blk, 0, stream>>>(xh, xl, 1024, 0, ewh, ewl, 1024, 0,
        enc_b, 0, 1.0f, nullptr, ench, encl, 512, 0, 1024);
    // 2. W1[n] = wq @ blk_w[n]   (z=8, 512x512, K=512)
    gemm_bs<0,1><<<dim3(4, 8, 8), blk, 0, stream>>>(iwh, iwl, 512, 0,
        bwTh, bwTl, 512, 262144, nullptr, 0, 1.0f,
        nullptr, W1h, W1l, 512, 262144, 512);
    // 3. qp1[n] = (enc @ W1[n]^T + bias1[n]) * 0.125    (z=8, 2048x512)
    gemm_bs<0,1><<<dim3(16, 8, 8), blk, 0, stream>>>(ench, encl, 512, 0,
        W1h, W1l, 512, 262144, bias1, 512, 0.125f,
        nullptr, qp1h, qp1l, 512, 1048576, 512);
    // 4. kv = memory @ [wk|wv]^T + [bk|bv]
    gemm_bs<0,1><<<dim3(2, 16, 1), blk, 0, stream>>>(memh, meml, 512, 0,
        iwh + 512 * 512, iwl + 512 * 512, 512, 0,
        in_b + 512, 0, 1.0f, nullptr, kvh, kvl, 1024, 0, 512);
    // 5. vpT planes
    transpose_vp2<<<dim3(512), blk, 0, stream>>>(kvh, kvl, vpTh, vpTl);
    // 6. fused MHA1 -> cbar split planes
    fused_attn<0><<<dim3(128, 8), blk, 110592, stream>>>(qp1h, qp1l, kvh, kvl,
        vpTh, vpTl, nullptr, cbh, cbl);
    // 7. u = cbar @ out_w^T + out_b  (f32 + split)
    gemm_bs<0,2><<<dim3(16, 8, 1), blk, 0, stream>>>(cbh, cbl, 512, 0, owh, owl, 512, 0,
        out_b, 0, 1.0f, uf, uh, ul, 512, 0, 512);
    // 8. qp2 = (enc @ wq^T + bq) * 0.125
    gemm_bs<0,1><<<dim3(16, 8, 1), blk, 0, stream>>>(ench, encl, 512, 0, iwh, iwl, 512, 0,
        in_b, 0, 0.125f, nullptr, qp2h, qp2l, 512, 0, 512);
    // 9. uvb = u @ wv^T
    gemm_bs<0,0><<<dim3(16, 8, 1), blk, 0, stream>>>(uh, ul, 512, 0,
        iwh + 1024 * 512, iwl + 1024 * 512, 512, 0,
        nullptr, 0, 1.0f, uvb, nullptr, nullptr, 512, 0, 512);
    // 10. fused MHA2 (+uv) -> c2 split planes
    fused_attn<1><<<dim3(16, 8), blk, 110592, stream>>>(qp2h, qp2l, kvh, kvl,
        vpTh, vpTl, uvb, c2h, c2l);
    // 11. updated_memory output (overwrites out-region scratch; last reader
    //     of qp1/W1/bwT was step 6)
    write_out1<<<dim3(4096), blk, 0, stream>>>(mem, uf, out1);
    // 12. W2 = dec_w @ out_w   (1024x512, K=512)
    gemm_bs<0,1><<<dim3(8, 8, 1), blk, 0, stream>>>(dwh, dwl, 512, 0,
        owTh, owTl, 512, 0, nullptr, 0, 1.0f,
        nullptr, W2h, W2l, 512, 0, 512);
    // 13. output = c2 @ W2^T + bias2
    gemm_bs<0,0><<<dim3(16, 16, 1), blk, 0, stream>>>(c2h, c2l, 512, 0, W2h, W2l, 512, 0,
        bias2, 0, 1.0f, out, nullptr, nullptr, 1024, 0, 512);
}

// Round 4
// 602.724 us; speedup vs baseline: 1.8490x; 1.1382x over previous
//
#include <hip/hip_runtime.h>
#include <math.h>

// ---------------------------------------------------------------------------
// MemoryAugmentedNetwork — R4: batched GEMMs + low-LDS fused attention
// Shapes: B=2048, IN=1024, E=512, M=256, NB=H=8, D=64
// Exact algebra (see R1-R3) plus: uvb = cb@(wv@out_w)^T + wv.out_b  (batches
// with u).  12 dispatches total.  Split-bf16 everywhere (C=AhBh+AhBl+AlBh).
// ---------------------------------------------------------------------------

typedef __attribute__((ext_vector_type(8))) short short8;
typedef __attribute__((ext_vector_type(4))) float f32x4;
typedef unsigned short u16;

__device__ inline u16 bf16_rn(float x) {
    unsigned u = __float_as_uint(x);
    unsigned r = (u + 0x7FFFu + ((u >> 16) & 1u)) >> 16;
    return (u16)r;
}
__device__ inline float bf16_f(u16 h) { return __uint_as_float(((unsigned)h) << 16); }

// ------------------ one kernel: split ALL f32 inputs to planes -------------
__global__ __launch_bounds__(256)
void split_all(const float* __restrict__ x, const float* __restrict__ mm,
               const float* __restrict__ ew, const float* __restrict__ iw,
               const float* __restrict__ ow, const float* __restrict__ dw,
               u16* __restrict__ xh, u16* __restrict__ xl,
               u16* __restrict__ mh, u16* __restrict__ ml,
               u16* __restrict__ ewh, u16* __restrict__ ewl,
               u16* __restrict__ iwh, u16* __restrict__ iwl,
               u16* __restrict__ owh, u16* __restrict__ owl,
               u16* __restrict__ dwh, u16* __restrict__ dwl)
{
    const long long total = 1081344;   // quads
    for (long long i = (long long)blockIdx.x * 256 + threadIdx.x; i < total;
         i += (long long)gridDim.x * 256) {
        const float* src; u16 *hi, *lo; long long j;
        if (i < 524288)      { src = x;  hi = xh;  lo = xl;  j = i; }
        else if (i < 557056) { src = mm; hi = mh;  lo = ml;  j = i - 524288; }
        else if (i < 688128) { src = ew; hi = ewh; lo = ewl; j = i - 557056; }
        else if (i < 884736) { src = iw; hi = iwh; lo = iwl; j = i - 688128; }
        else if (i < 950272) { src = ow; hi = owh; lo = owl; j = i - 884736; }
        else                 { src = dw; hi = dwh; lo = dwl; j = i - 950272; }
        float4 v = reinterpret_cast<const float4*>(src)[j];
        u16 h0 = bf16_rn(v.x), h1 = bf16_rn(v.y), h2 = bf16_rn(v.z), h3 = bf16_rn(v.w);
        ushort4 hv = {h0, h1, h2, h3};
        ushort4 lv = {bf16_rn(v.x - bf16_f(h0)), bf16_rn(v.y - bf16_f(h1)),
                      bf16_rn(v.z - bf16_f(h2)), bf16_rn(v.w - bf16_f(h3))};
        reinterpret_cast<ushort4*>(hi)[j] = hv;
        reinterpret_cast<ushort4*>(lo)[j] = lv;
    }
}

// ---- transpose+split blk_w (z<8) and out_w (z=8): [512][512] -> [c][r] ----
__global__ __launch_bounds__(256)
void tr_split9(const float* __restrict__ blk_w, const float* __restrict__ out_w,
               u16* __restrict__ bwTh, u16* __restrict__ bwTl,
               u16* __restrict__ owTh, u16* __restrict__ owTl)
{
    __shared__ float T[32][33];
    const int z = blockIdx.z;
    const float* s; u16 *dh, *dl;
    if (z < 8) { s = blk_w + (long long)z * 262144; dh = bwTh + (long long)z * 262144; dl = bwTl + (long long)z * 262144; }
    else       { s = out_w; dh = owTh; dl = owTl; }
    const int c0 = blockIdx.x * 32, r0 = blockIdx.y * 32;
    const int tx = threadIdx.x & 31, ty = threadIdx.x >> 5;
    #pragma unroll
    for (int rr = 0; rr < 4; ++rr)
        T[ty + rr * 8][tx] = s[(long long)(r0 + ty + rr * 8) * 512 + c0 + tx];
    __syncthreads();
    #pragma unroll
    for (int rr = 0; rr < 4; ++rr) {
        float v = T[tx][ty + rr * 8];
        long long o = (long long)(c0 + ty + rr * 8) * 512 + r0 + tx;
        u16 hh = bf16_rn(v);
        dh[o] = hh; dl[o] = bf16_rn(v - bf16_f(hh));
    }
}

// ----------- bias precomputes: bias1[8][512], bias2[1024], bias_uv[512] ----
__global__ __launch_bounds__(256)
void bias_misc(const float* __restrict__ in_w, const float* __restrict__ in_b,
               const float* __restrict__ blk_b,
               const float* __restrict__ dec_w, const float* __restrict__ out_b,
               const float* __restrict__ dec_b,
               float* __restrict__ bias1, float* __restrict__ bias2,
               float* __restrict__ bias_uv)
{
    int idx = blockIdx.x * 256 + threadIdx.x;   // 5632
    if (idx < 4096) {
        int n = idx >> 9, f = idx & 511;
        const float* wr_ = in_w + (long long)f * 512;     // wq row f
        const float* bb  = blk_b + n * 512;
        float s = in_b[f];
        for (int o = 0; o < 512; ++o) s += wr_[o] * bb[o];
        bias1[idx] = s;
    } else if (idx < 5120) {
        int i = idx - 4096;
        const float* dr = dec_w + (long long)i * 512;
        float s = dec_b[i];
        for (int f = 0; f < 512; ++f) s += dr[f] * out_b[f];
        bias2[i] = s;
    } else if (idx < 5632) {
        int f = idx - 5120;
        const float* wv = in_w + (long long)(1024 + f) * 512;
        float s = 0.f;
        for (int e = 0; e < 512; ++e) s += wv[e] * out_b[e];
        bias_uv[f] = s;
    }
}

// ------------------- split-bf16 MFMA GEMM:  C = A @ B^T --------------------
// (single-desc version; used for enc [ACT=1] and final out)
template<int ACT, int OUT>
__global__ __launch_bounds__(256)
void gemm_bs(const u16* __restrict__ Ah, const u16* __restrict__ Al,
             int lda, const u16* __restrict__ Bh, const u16* __restrict__ Bl,
             int ldb, const float* __restrict__ bias, float scale,
             float* __restrict__ Cf, u16* __restrict__ Ch, u16* __restrict__ Cl,
             int ldc, int K)
{
    __shared__ u16 Ash[128][40];
    __shared__ u16 Asl[128][40];
    __shared__ u16 Bsh[64][40];
    __shared__ u16 Bsl[64][40];

    const int m0 = blockIdx.x * 128;
    const int n0 = blockIdx.y * 64;
    const int t  = threadIdx.x;
    const int r  = t >> 2;
    const int ck = (t & 3) << 3;
    const int lane = t & 63;
    const int wid  = t >> 6;
    const int wr = (wid >> 1) * 64;
    const int wc = (wid & 1) * 32;
    const int lr = lane & 15;
    const int lk = (lane >> 4) << 3;

    f32x4 acc[4][2];
    const f32x4 zero = {0.f, 0.f, 0.f, 0.f};
    #pragma unroll
    for (int i = 0; i < 4; ++i)
        #pragma unroll
        for (int j = 0; j < 2; ++j) acc[i][j] = zero;

    const long long arow0 = (long long)(m0 + r) * lda;
    const long long arow1 = (long long)(m0 + r + 64) * lda;
    const long long brow  = (long long)(n0 + r) * ldb;

    for (int k0 = 0; k0 < K; k0 += 32) {
        int4 vah0 = *reinterpret_cast<const int4*>(Ah + arow0 + k0 + ck);
        int4 vah1 = *reinterpret_cast<const int4*>(Ah + arow1 + k0 + ck);
        int4 val0 = *reinterpret_cast<const int4*>(Al + arow0 + k0 + ck);
        int4 val1 = *reinterpret_cast<const int4*>(Al + arow1 + k0 + ck);
        int4 vbh  = *reinterpret_cast<const int4*>(Bh + brow  + k0 + ck);
        int4 vbl  = *reinterpret_cast<const int4*>(Bl + brow  + k0 + ck);
        __syncthreads();
        *reinterpret_cast<int4*>(&Ash[r][ck])      = vah0;
        *reinterpret_cast<int4*>(&Ash[r + 64][ck]) = vah1;
        *reinterpret_cast<int4*>(&Asl[r][ck])      = val0;
        *reinterpret_cast<int4*>(&Asl[r + 64][ck]) = val1;
        *reinterpret_cast<int4*>(&Bsh[r][ck])      = vbh;
        *reinterpret_cast<int4*>(&Bsl[r][ck])      = vbl;
        __syncthreads();

        short8 fah[4], fal[4], fbh[2], fbl[2];
        #pragma unroll
        for (int i = 0; i < 4; ++i) {
            fah[i] = *reinterpret_cast<const short8*>(&Ash[wr + i * 16 + lr][lk]);
            fal[i] = *reinterpret_cast<const short8*>(&Asl[wr + i * 16 + lr][lk]);
        }
        #pragma unroll
        for (int j = 0; j < 2; ++j) {
            fbh[j] = *reinterpret_cast<const short8*>(&Bsh[wc + j * 16 + lr][lk]);
            fbl[j] = *reinterpret_cast<const short8*>(&Bsl[wc + j * 16 + lr][lk]);
        }
        #pragma unroll
        for (int i = 0; i < 4; ++i)
            #pragma unroll
            for (int j = 0; j < 2; ++j) {
                acc[i][j] = __builtin_amdgcn_mfma_f32_16x16x32_bf16(fah[i], fbh[j], acc[i][j], 0, 0, 0);
                acc[i][j] = __builtin_amdgcn_mfma_f32_16x16x32_bf16(fah[i], fbl[j], acc[i][j], 0, 0, 0);
                acc[i][j] = __builtin_amdgcn_mfma_f32_16x16x32_bf16(fal[i], fbh[j], acc[i][j], 0, 0, 0);
            }
    }

    #pragma unroll
    for (int j = 0; j < 2; ++j) {
        const int col = n0 + wc + j * 16 + lr;
        const float bv = bias ? bias[col] : 0.f;
        #pragma unroll
        for (int i = 0; i < 4; ++i) {
            #pragma unroll
            for (int q = 0; q < 4; ++q) {
                const int row = m0 + wr + i * 16 + ((lane >> 4) << 2) + q;
                float v = (acc[i][j][q] + bv) * scale;
                if (ACT) v = tanhf(v);
                const long long off = (long long)row * ldc + col;
                if (OUT == 0 || OUT == 2) Cf[off] = v;
                if (OUT >= 1) {
                    u16 h = bf16_rn(v);
                    Ch[off] = h;
                    Cl[off] = bf16_rn(v - bf16_f(h));
                }
            }
        }
    }
}

// ----------------- descriptor-batched GEMM (K=512, lda=ldb=512) ------------
struct ZD {
    const u16 *Ah, *Al, *Bh, *Bl;
    const float* bias;
    float* Cf; u16 *Ch; u16 *Cl;
    int M, ldc; float scale;
};
template<int NZ> struct ZPack { ZD d[NZ]; };

template<int OUT, int NZ>
__global__ __launch_bounds__(256)
void gemm_multi(ZPack<NZ> pk)
{
    const ZD dz = pk.d[blockIdx.z];
    const int m0 = blockIdx.x * 128;
    if (m0 >= dz.M) return;

    __shared__ u16 Ash[128][40];
    __shared__ u16 Asl[128][40];
    __shared__ u16 Bsh[64][40];
    __shared__ u16 Bsl[64][40];

    const int n0 = blockIdx.y * 64;
    const int t  = threadIdx.x;
    const int r  = t >> 2;
    const int ck = (t & 3) << 3;
    const int lane = t & 63;
    const int wid  = t >> 6;
    const int wr = (wid >> 1) * 64;
    const int wc = (wid & 1) * 32;
    const int lr = lane & 15;
    const int lk = (lane >> 4) << 3;

    f32x4 acc[4][2];
    const f32x4 zero = {0.f, 0.f, 0.f, 0.f};
    #pragma unroll
    for (int i = 0; i < 4; ++i)
        #pragma unroll
        for (int j = 0; j < 2; ++j) acc[i][j] = zero;

    const long long arow0 = (long long)(m0 + r) * 512;
    const long long arow1 = (long long)(m0 + r + 64) * 512;
    const long long brow  = (long long)(n0 + r) * 512;

    for (int k0 = 0; k0 < 512; k0 += 32) {
        int4 vah0 = *reinterpret_cast<const int4*>(dz.Ah + arow0 + k0 + ck);
        int4 vah1 = *reinterpret_cast<const int4*>(dz.Ah + arow1 + k0 + ck);
        int4 val0 = *reinterpret_cast<const int4*>(dz.Al + arow0 + k0 + ck);
        int4 val1 = *reinterpret_cast<const int4*>(dz.Al + arow1 + k0 + ck);
        int4 vbh  = *reinterpret_cast<const int4*>(dz.Bh + brow  + k0 + ck);
        int4 vbl  = *reinterpret_cast<const int4*>(dz.Bl + brow  + k0 + ck);
        __syncthreads();
        *reinterpret_cast<int4*>(&Ash[r][ck])      = vah0;
        *reinterpret_cast<int4*>(&Ash[r + 64][ck]) = vah1;
        *reinterpret_cast<int4*>(&Asl[r][ck])      = val0;
        *reinterpret_cast<int4*>(&Asl[r + 64][ck]) = val1;
        *reinterpret_cast<int4*>(&Bsh[r][ck])      = vbh;
        *reinterpret_cast<int4*>(&Bsl[r][ck])      = vbl;
        __syncthreads();

        short8 fah[4], fal[4], fbh[2], fbl[2];
        #pragma unroll
        for (int i = 0; i < 4; ++i) {
            fah[i] = *reinterpret_cast<const short8*>(&Ash[wr + i * 16 + lr][lk]);
            fal[i] = *reinterpret_cast<const short8*>(&Asl[wr + i * 16 + lr][lk]);
        }
        #pragma unroll
        for (int j = 0; j < 2; ++j) {
            fbh[j] = *reinterpret_cast<const short8*>(&Bsh[wc + j * 16 + lr][lk]);
            fbl[j] = *reinterpret_cast<const short8*>(&Bsl[wc + j * 16 + lr][lk]);
        }
        #pragma unroll
        for (int i = 0; i < 4; ++i)
            #pragma unroll
            for (int j = 0; j < 2; ++j) {
                acc[i][j] = __builtin_amdgcn_mfma_f32_16x16x32_bf16(fah[i], fbh[j], acc[i][j], 0, 0, 0);
                acc[i][j] = __builtin_amdgcn_mfma_f32_16x16x32_bf16(fah[i], fbl[j], acc[i][j], 0, 0, 0);
                acc[i][j] = __builtin_amdgcn_mfma_f32_16x16x32_bf16(fal[i], fbh[j], acc[i][j], 0, 0, 0);
            }
    }

    #pragma unroll
    for (int j = 0; j < 2; ++j) {
        const int col = n0 + wc + j * 16 + lr;
        const float bv = dz.bias ? dz.bias[col] : 0.f;
        #pragma unroll
        for (int i = 0; i < 4; ++i) {
            #pragma unroll
            for (int q = 0; q < 4; ++q) {
                const int row = m0 + wr + i * 16 + ((lane >> 4) << 2) + q;
                float v = (acc[i][j][q] + bv) * dz.scale;
                const long long off = (long long)row * dz.ldc + col;
                if (OUT == 0) dz.Cf[off] = v;
                else {
                    u16 h = bf16_rn(v);
                    dz.Ch[off] = h;
                    dz.Cl[off] = bf16_rn(v - bf16_f(h));
                }
            }
        }
    }
}

// vpT[h][d][m] = kv[m][512 + h*64 + d], both planes
__global__ __launch_bounds__(256)
void transpose_vp2(const u16* __restrict__ kvh, const u16* __restrict__ kvl,
                   u16* __restrict__ vpTh, u16* __restrict__ vpTl)
{
    int idx = blockIdx.x * 256 + threadIdx.x;   // 131072
    int m = idx & 255;
    int rest = idx >> 8;
    int d = rest & 63;
    int h = rest >> 6;
    int src = m * 1024 + 512 + h * 64 + d;
    vpTh[idx] = kvh[src];
    vpTl[idx] = kvl[src];
}

// ------------------------- fused attention (72 KB LDS, 2 wg/CU) ------------
// 128 q-rows x 256 keys x 64 d; K staged in 2 halves; PV in 4 key-quarters.
// MODE 0: Q = qp1 [q][2048][512] slice, rows = q*16+bb; epilogue q-mean.
// MODE 1: Q = qp2 [2048][512]; epilogue +uv.
template<int MODE>
__global__ __launch_bounds__(256, 2)
void fused_attn(const u16* __restrict__ Qph, const u16* __restrict__ Qpl,
                const u16* __restrict__ Kvh, const u16* __restrict__ Kvl,
                const u16* __restrict__ VTh, const u16* __restrict__ VTl,
                const float* __restrict__ uv,
                u16* __restrict__ Oh, u16* __restrict__ Ol)
{
    extern __shared__ char smem[];   // 73728 B
    const int h = blockIdx.y;
    const int t = threadIdx.x;
    const int lane = t & 63, w = t >> 6;
    const int l15 = lane & 15, g = lane >> 4;
    const int wr = w * 32;
    const int b0 = blockIdx.x * (MODE == 0 ? 16 : 128);

    u16* Qs = (u16*)smem;            // [2][128][72] = 36864 B
    char* KsB = smem + 36864;        // [2][128][72] u16 = 36864 B

    // stage Q (held through S phase)
    for (int c = t; c < 2048; c += 256) {
        int plane = c >> 10, rem = c & 1023;
        int row = rem >> 3, seg = rem & 7;
        const u16* src = plane ? Qpl : Qph;
        long long addr;
        if (MODE == 0) {
            int q = row >> 4, bb = row & 15;
            addr = ((long long)q * 2048 + b0 + bb) * 512 + h * 64 + seg * 8;
        } else {
            addr = (long long)(b0 + row) * 512 + h * 64 + seg * 8;
        }
        *(int4*)(&Qs[plane * 9216 + row * 72 + seg * 8]) = *(const int4*)(src + addr);
    }

    f32x4 sacc[2][16];
    const f32x4 zero = {0.f, 0.f, 0.f, 0.f};
    #pragma unroll
    for (int i = 0; i < 2; ++i)
        #pragma unroll
        for (int j = 0; j < 16; ++j) sacc[i][j] = zero;

    short8 qfh[2][2], qfl[2][2];

    for (int kh = 0; kh < 2; ++kh) {
        if (kh) __syncthreads();     // all waves done with Ks half 0
        for (int c = t; c < 2048; c += 256) {
            int plane = c >> 10, rem = c & 1023;
            int key = rem >> 3, seg = rem & 7;
            const u16* src = plane ? Kvl : Kvh;
            *(int4*)(KsB + plane * 18432 + key * 144 + seg * 16) =
                *(const int4*)(src + (long long)(kh * 128 + key) * 1024 + h * 64 + seg * 8);
        }
        __syncthreads();
        if (kh == 0) {
            #pragma unroll
            for (int i = 0; i < 2; ++i)
                #pragma unroll
                for (int kf = 0; kf < 2; ++kf) {
                    int ro = (wr + 16 * i + l15) * 72 + kf * 32 + g * 8;
                    qfh[i][kf] = *(const short8*)(&Qs[ro]);
                    qfl[i][kf] = *(const short8*)(&Qs[9216 + ro]);
                }
        }
        #pragma unroll
        for (int j = 0; j < 8; ++j) {
            int jg = kh * 8 + j;
            #pragma unroll
            for (int kf = 0; kf < 2; ++kf) {
                const char* kb = KsB + (j * 16 + l15) * 144 + (kf * 32 + g * 8) * 2;
                short8 kbh = *(const short8*)(kb);
                short8 kbl = *(const short8*)(kb + 18432);
                #pragma unroll
                for (int i = 0; i < 2; ++i) {
                    sacc[i][jg] = __builtin_amdgcn_mfma_f32_16x16x32_bf16(qfh[i][kf], kbh, sacc[i][jg], 0, 0, 0);
                    sacc[i][jg] = __builtin_amdgcn_mfma_f32_16x16x32_bf16(qfh[i][kf], kbl, sacc[i][jg], 0, 0, 0);
                    sacc[i][jg] = __builtin_amdgcn_mfma_f32_16x16x32_bf16(qfl[i][kf], kbh, sacc[i][jg], 0, 0, 0);
                }
            }
        }
    }

    // softmax: row r = wr+16i+4g+q lives on 16 lanes (l15); reduce over l15
    float inv[2][4];
    #pragma unroll
    for (int i = 0; i < 2; ++i)
        #pragma unroll
        for (int q = 0; q < 4; ++q) {
            float m = -1e30f;
            #pragma unroll
            for (int j = 0; j < 16; ++j) m = fmaxf(m, sacc[i][j][q]);
            #pragma unroll
            for (int off = 1; off <= 8; off <<= 1) m = fmaxf(m, __shfl_xor(m, off, 64));
            #pragma unroll
            for (int j = 0; j < 16; ++j) sacc[i][j][q] = __expf(sacc[i][j][q] - m);
            float s = 0.f;
            #pragma unroll
            for (int j = 0; j < 16; ++j) s += sacc[i][j][q];
            #pragma unroll
            for (int off = 1; off <= 8; off <<= 1) s += __shfl_xor(s, off, 64);
            inv[i][q] = 1.0f / s;
        }

    // PV: 4 key-quarters; P -> smem[0,32768), VT -> smem+36864 [2][64][64]
    f32x4 ctx[2][4];
    #pragma unroll
    for (int i = 0; i < 2; ++i)
        #pragma unroll
        for (int jd = 0; jd < 4; ++jd) ctx[i][jd] = zero;

    for (int qt = 0; qt < 4; ++qt) {
        __syncthreads();   // prior readers of Qs/Ks (qt=0) or P/VT (qt>0) done
        #pragma unroll
        for (int i = 0; i < 2; ++i)
            #pragma unroll
            for (int jj = 0; jj < 4; ++jj) {
                int jg = qt * 4 + jj;
                #pragma unroll
                for (int q = 0; q < 4; ++q) {
                    int row = wr + 16 * i + 4 * g + q;
                    int key = jj * 16 + l15;
                    float pv = sacc[i][jg][q];
                    u16 ph = bf16_rn(pv);
                    u16 pl = bf16_rn(pv - bf16_f(ph));
                    int byt = row * 128 + ((key * 2) ^ ((row & 7) << 4));
                    *(u16*)(smem + byt) = ph;
                    *(u16*)(smem + 16384 + byt) = pl;
                }
            }
        for (int c = t; c < 1024; c += 256) {
            int plane = c >> 9, rem = c & 511;
            int d = rem >> 3, seg = rem & 7;
            const u16* src = plane ? VTl : VTh;
            int4 v = *(const int4*)(src + (long long)h * 16384 + d * 256 + qt * 64 + seg * 8);
            int byt = 36864 + plane * 8192 + d * 128 + ((seg * 16) ^ ((d & 7) << 4));
            *(int4*)(smem + byt) = v;
        }
        __syncthreads();

        short8 pah[2][2], pal[2][2];
        #pragma unroll
        for (int i = 0; i < 2; ++i)
            #pragma unroll
            for (int kf = 0; kf < 2; ++kf) {
                int row = wr + 16 * i + l15;
                int byt = row * 128 + ((kf * 64 + g * 16) ^ ((row & 7) << 4));
                pah[i][kf] = *(const short8*)(smem + byt);
                pal[i][kf] = *(const short8*)(smem + 16384 + byt);
            }
        #pragma unroll
        for (int jd = 0; jd < 4; ++jd) {
            #pragma unroll
            for (int kf = 0; kf < 2; ++kf) {
                int d = 16 * jd + l15;
                int byt = 36864 + d * 128 + ((kf * 64 + g * 16) ^ ((d & 7) << 4));
                short8 vbh = *(const short8*)(smem + byt);
                short8 vbl = *(const short8*)(smem + 8192 + byt);
                #pragma unroll
                for (int i = 0; i < 2; ++i) {
                    ctx[i][jd] = __builtin_amdgcn_mfma_f32_16x16x32_bf16(pah[i][kf], vbh, ctx[i][jd], 0, 0, 0);
                    ctx[i][jd] = __builtin_amdgcn_mfma_f32_16x16x32_bf16(pah[i][kf], vbl, ctx[i][jd], 0, 0, 0);
                    ctx[i][jd] = __builtin_amdgcn_mfma_f32_16x16x32_bf16(pal[i][kf], vbh, ctx[i][jd], 0, 0, 0);
                }
            }
        }
    }

    // epilogue
    if (MODE == 0) {
        __syncthreads();
        float* R = (float*)smem;   // [8 q][16 b][64 d] = 32 KB
        #pragma unroll
        for (int i = 0; i < 2; ++i)
            #pragma unroll
            for (int jd = 0; jd < 4; ++jd)
                #pragma unroll
                for (int q = 0; q < 4; ++q) {
                    int qa = 2 * w + i;
                    int bb = 4 * g + q;
                    int d  = 16 * jd + l15;
                    R[qa * 1024 + bb * 64 + d] = ctx[i][jd][q] * inv[i][q];
                }
        __syncthreads();
        for (int o = t; o < 1024; o += 256) {
            int bb = o >> 6, d = o & 63;
            float s = 0.f;
            #pragma unroll
            for (int qa = 0; qa < 8; ++qa) s += R[qa * 1024 + bb * 64 + d];
            s *= 0.125f;
            long long addr = (long long)(b0 + bb) * 512 + h * 64 + d;
            u16 hh = bf16_rn(s);
            Oh[addr] = hh;
            Ol[addr] = bf16_rn(s - bf16_f(hh));
        }
    } else {
        #pragma unroll
        for (int i = 0; i < 2; ++i)
            #pragma unroll
            for (int jd = 0; jd < 4; ++jd)
                #pragma unroll
                for (int q = 0; q < 4; ++q) {
                    int b = b0 + wr + 16 * i + 4 * g + q;
                    int d = 16 * jd + l15;
                    long long addr = (long long)b * 512 + h * 64 + d;
                    float v = ctx[i][jd][q] * inv[i][q] + uv[addr];
                    u16 hh = bf16_rn(v);
                    Oh[addr] = hh;
                    Ol[addr] = bf16_rn(v - bf16_f(hh));
                }
    }
}

// out1[b][m][e] = memory[m][e] + u[b][e]
__global__ __launch_bounds__(256)
void write_out1(const float* __restrict__ mem, const float* __restrict__ u,
                float* __restrict__ out1)
{
    const float4* m4 = reinterpret_cast<const float4*>(mem);
    const float4* u4 = reinterpret_cast<const float4*>(u);
    float4* o4 = reinterpret_cast<float4*>(out1);
    const long long total = 2048LL * 256 * 128;
    for (long long i = (long long)blockIdx.x * 256 + threadIdx.x; i < total;
         i += (long long)gridDim.x * 256) {
        int e4 = (int)(i & 127);
        int m  = (int)((i >> 7) & 255);
        long long b = i >> 15;
        float4 a = m4[m * 128 + e4];
        float4 c = u4[b * 128 + e4];
        float4 rr = {a.x + c.x, a.y + c.y, a.z + c.z, a.w + c.w};
        o4[i] = rr;
    }
}

extern "C" void kernel_launch(void* const* d_in, const int* in_sizes, int n_in,
                              void* d_out, int out_size, void* d_ws, size_t ws_size,
                              hipStream_t stream)
{
    (void)in_sizes; (void)n_in; (void)out_size; (void)ws_size;
    const float* x     = (const float*)d_in[0];
    const float* mem   = (const float*)d_in[1];
    const float* enc_w = (const float*)d_in[2];
    const float* enc_b = (const float*)d_in[3];
    const float* blk_w = (const float*)d_in[4];
    const float* blk_b = (const float*)d_in[5];
    const float* in_w  = (const float*)d_in[6];
    const float* in_b  = (const float*)d_in[7];
    const float* out_w = (const float*)d_in[8];
    const float* out_b = (const float*)d_in[9];
    const float* dec_w = (const float*)d_in[10];
    const float* dec_b = (const float*)d_in[11];
    float* out = (float*)d_out;

    // ---------------- workspace carve-up (256B-aligned) --------------------
    char* p = (char*)d_ws;
    auto alloc = [&](size_t bytes) { char* q = p; p += (bytes + 255) & ~(size_t)255; return q; };
    u16* xh   = (u16*)alloc(2097152 * 2); u16* xl   = (u16*)alloc(2097152 * 2);
    u16* memh = (u16*)alloc(131072 * 2);  u16* meml = (u16*)alloc(131072 * 2);
    u16* ewh  = (u16*)alloc(524288 * 2);  u16* ewl  = (u16*)alloc(524288 * 2);
    u16* iwh  = (u16*)alloc(786432 * 2);  u16* iwl  = (u16*)alloc(786432 * 2);
    u16* owh  = (u16*)alloc(262144 * 2);  u16* owl  = (u16*)alloc(262144 * 2);
    u16* owTh = (u16*)alloc(262144 * 2);  u16* owTl = (u16*)alloc(262144 * 2);
    u16* dwh  = (u16*)alloc(524288 * 2);  u16* dwl  = (u16*)alloc(524288 * 2);
    u16* ench = (u16*)alloc(1048576 * 2); u16* encl = (u16*)alloc(1048576 * 2);
    u16* kvh  = (u16*)alloc(262144 * 2);  u16* kvl  = (u16*)alloc(262144 * 2);
    u16* vpTh = (u16*)alloc(131072 * 2);  u16* vpTl = (u16*)alloc(131072 * 2);
    float* bias1  = (float*)alloc(4096 * 4);
    float* bias2  = (float*)alloc(1024 * 4);
    float* biasuv = (float*)alloc(512 * 4);
    u16* cbh  = (u16*)alloc(1048576 * 2); u16* cbl  = (u16*)alloc(1048576 * 2);
    float* uf = (float*)alloc(1048576 * 4);
    u16* qp2h = (u16*)alloc(1048576 * 2); u16* qp2l = (u16*)alloc(1048576 * 2);
    float* uvb = (float*)alloc(1048576 * 4);
    u16* c2h  = (u16*)alloc(1048576 * 2); u16* c2l  = (u16*)alloc(1048576 * 2);
    u16* W2h  = (u16*)alloc(524288 * 2);  u16* W2l  = (u16*)alloc(524288 * 2);
    u16* Wuvh = (u16*)alloc(262144 * 2);  u16* Wuvl = (u16*)alloc(262144 * 2);

    // ------ big scratch in the not-yet-written updated_memory region -------
    float* out1 = out + 2097152;
    u16* bwTh = (u16*)out1;               // [8][512][512]
    u16* bwTl = bwTh + 2097152;
    u16* W1h  = bwTl + 2097152;           // [8][512][512]
    u16* W1l  = W1h + 2097152;
    u16* qp1h = W1l + 2097152;            // [8][2048][512]
    u16* qp1l = qp1h + 8388608;

    dim3 blk(256);

    // 1. split all f32 inputs to hi/lo planes
    split_all<<<dim3(2048), blk, 0, stream>>>(x, mem, enc_w, in_w, out_w, dec_w,
        xh, xl, memh, meml, ewh, ewl, iwh, iwl, owh, owl, dwh, dwl);
    // 2. transposes (blk_w x8, out_w)
    tr_split9<<<dim3(16, 16, 9), blk, 0, stream>>>(blk_w, out_w, bwTh, bwTl, owTh, owTl);
    // 3. folded biases
    bias_misc<<<dim3(22), blk, 0, stream>>>(in_w, in_b, blk_b, dec_w, out_b, dec_b,
                                            bias1, bias2, biasuv);
    // 4. encoded = tanh(x @ enc_w^T + enc_b)
    gemm_bs<1,1><<<dim3(16, 8, 1), blk, 0, stream>>>(xh, xl, 1024, ewh, ewl, 1024,
        enc_b, 1.0f, nullptr, ench, encl, 512, 1024);
    // 5. mega-batch: W1 x8, Wuv, W2 x2, kv x2   (z=13)
    {
        ZPack<13> pk;
        for (int z = 0; z < 8; ++z)
            pk.d[z] = { iwh, iwl, bwTh + (long long)z * 262144, bwTl + (long long)z * 262144,
                        nullptr, nullptr, W1h + (long long)z * 262144, W1l + (long long)z * 262144,
                        512, 512, 1.0f };
        pk.d[8]  = { iwh + 1024 * 512, iwl + 1024 * 512, owTh, owTl, nullptr,
                     nullptr, Wuvh, Wuvl, 512, 512, 1.0f };
        pk.d[9]  = { dwh, dwl, owTh, owTl, nullptr, nullptr, W2h, W2l, 512, 512, 1.0f };
        pk.d[10] = { dwh + 512 * 512, dwl + 512 * 512, owTh, owTl, nullptr,
                     nullptr, W2h + 512 * 512, W2l + 512 * 512, 512, 512, 1.0f };
        pk.d[11] = { memh, meml, iwh + 512 * 512, iwl + 512 * 512, in_b + 512,
                     nullptr, kvh, kvl, 256, 1024, 1.0f };
        pk.d[12] = { memh, meml, iwh + 1024 * 512, iwl + 1024 * 512, in_b + 1024,
                     nullptr, kvh + 512, kvl + 512, 256, 1024, 1.0f };
        gemm_multi<1,13><<<dim3(4, 8, 13), blk, 0, stream>>>(pk);
    }
    // 6. vpT planes
    transpose_vp2<<<dim3(512), blk, 0, stream>>>(kvh, kvl, vpTh, vpTl);
    // 7. qp1 x8 + qp2   (z=9, scale 0.125 folded)
    {
        ZPack<9> pk;
        for (int z = 0; z < 8; ++z)
            pk.d[z] = { ench, encl, W1h + (long long)z * 262144, W1l + (long long)z * 262144,
                        bias1 + z * 512, nullptr,
                        qp1h + (long long)z * 1048576, qp1l + (long long)z * 1048576,
                        2048, 512, 0.125f };
        pk.d[8] = { ench, encl, iwh, iwl, in_b, nullptr, qp2h, qp2l, 2048, 512, 0.125f };
        gemm_multi<1,9><<<dim3(16, 8, 9), blk, 0, stream>>>(pk);
    }
    // 8. fused MHA1 -> cbar planes
    fused_attn<0><<<dim3(128, 8), blk, 73728, stream>>>(qp1h, qp1l, kvh, kvl,
        vpTh, vpTl, nullptr, cbh, cbl);
    // 9. u + uvb (batched, both from cbar)
    {
        ZPack<2> pk;
        pk.d[0] = { cbh, cbl, owh, owl, out_b, uf, nullptr, nullptr, 2048, 512, 1.0f };
        pk.d[1] = { cbh, cbl, Wuvh, Wuvl, biasuv, uvb, nullptr, nullptr, 2048, 512, 1.0f };
        gemm_multi<0,2><<<dim3(16, 8, 2), blk, 0, stream>>>(pk);
    }
    // 10. fused MHA2 (+uv) -> c2 planes
    fused_attn<1><<<dim3(16, 8), blk, 73728, stream>>>(qp2h, qp2l, kvh, kvl,
        vpTh, vpTl, uvb, c2h, c2l);
    // 11. updated_memory output (after last out-region scratch reader: step 8)
    write_out1<<<dim3(4096), blk, 0, stream>>>(mem, uf, out1);
    // 12. output = c2 @ W2^T + bias2
    gemm_bs<0,0><<<dim3(16, 16, 1), blk, 0, stream>>>(c2h, c2l, 512, W2h, W2l, 512,
        bias2, 1.0f, out, nullptr, nullptr, 1024, 512);
}

// Round 5
// 492.752 us; speedup vs baseline: 2.2616x; 1.2232x over previous
//
#include <hip/hip_runtime.h>
#include <math.h>

// ---------------------------------------------------------------------------
// MemoryAugmentedNetwork — R5: 7 dispatches; HBM-bound output write carries
// compute riders (attn2, final GEMM) as co-scheduled blocks.
// Shapes: B=2048, IN=1024, E=512, M=256, NB=H=8, D=64
// Algebra (exact, see R1-R4): shared K/V; mean->out_w commute; MHA2 collapse;
// W1=wq@blk_w, Wuv=wv@out_w, W2=dec_w@out_w; folded biases.
// Numerics: split-bf16 (a=ah+al), C=AhBh+AhBl+AlBh, f32 accum.
// ---------------------------------------------------------------------------

typedef __attribute__((ext_vector_type(8))) short short8;
typedef __attribute__((ext_vector_type(4))) float f32x4;
typedef unsigned short u16;

__device__ inline u16 bf16_rn(float x) {
    unsigned u = __float_as_uint(x);
    unsigned r = (u + 0x7FFFu + ((u >> 16) & 1u)) >> 16;
    return (u16)r;
}
__device__ inline float bf16_f(u16 h) { return __uint_as_float(((unsigned)h) << 16); }

// ======================= prep: split + transpose + bias ====================
// blocks [0,2304): tr_split tiles (blk_w x8 z<8, out_w z=8)
// blocks [2304,2326): bias precomputes
// blocks [2326,4374): split_all grid-stride
__global__ __launch_bounds__(256)
void prep_all(const float* __restrict__ x, const float* __restrict__ mm,
              const float* __restrict__ ew, const float* __restrict__ iw,
              const float* __restrict__ ow, const float* __restrict__ dw,
              const float* __restrict__ blk_w,
              const float* __restrict__ in_b, const float* __restrict__ blk_b,
              const float* __restrict__ out_b, const float* __restrict__ dec_b,
              u16* __restrict__ xh, u16* __restrict__ xl,
              u16* __restrict__ mh, u16* __restrict__ ml,
              u16* __restrict__ ewh, u16* __restrict__ ewl,
              u16* __restrict__ iwh, u16* __restrict__ iwl,
              u16* __restrict__ owh, u16* __restrict__ owl,
              u16* __restrict__ dwh, u16* __restrict__ dwl,
              u16* __restrict__ bwTh, u16* __restrict__ bwTl,
              u16* __restrict__ owTh, u16* __restrict__ owTl,
              float* __restrict__ bias1, float* __restrict__ bias2,
              float* __restrict__ bias_uv)
{
    __shared__ float T[32][33];
    const int id = blockIdx.x;
    const int t = threadIdx.x;
    if (id < 2304) {
        // transpose+split [512][512] -> [c][r] planes
        const int z = id >> 8, within = id & 255;
        const float* s; u16 *dh, *dl;
        if (z < 8) { s = blk_w + (long long)z * 262144;
                     dh = bwTh + (long long)z * 262144; dl = bwTl + (long long)z * 262144; }
        else       { s = ow; dh = owTh; dl = owTl; }
        const int c0 = (within & 15) * 32, r0 = (within >> 4) * 32;
        const int tx = t & 31, ty = t >> 5;
        #pragma unroll
        for (int rr = 0; rr < 4; ++rr)
            T[ty + rr * 8][tx] = s[(long long)(r0 + ty + rr * 8) * 512 + c0 + tx];
        __syncthreads();
        #pragma unroll
        for (int rr = 0; rr < 4; ++rr) {
            float v = T[tx][ty + rr * 8];
            long long o = (long long)(c0 + ty + rr * 8) * 512 + r0 + tx;
            u16 hh = bf16_rn(v);
            dh[o] = hh; dl[o] = bf16_rn(v - bf16_f(hh));
        }
    } else if (id < 2326) {
        int idx = (id - 2304) * 256 + t;   // 5632
        if (idx < 4096) {
            int n = idx >> 9, f = idx & 511;
            const float* wr_ = iw + (long long)f * 512;
            const float* bb  = blk_b + n * 512;
            float s = in_b[f];
            for (int o = 0; o < 512; ++o) s += wr_[o] * bb[o];
            bias1[idx] = s;
        } else if (idx < 5120) {
            int i = idx - 4096;
            const float* dr = dw + (long long)i * 512;
            float s = dec_b[i];
            for (int f = 0; f < 512; ++f) s += dr[f] * out_b[f];
            bias2[i] = s;
        } else if (idx < 5632) {
            int f = idx - 5120;
            const float* wv = iw + (long long)(1024 + f) * 512;
            float s = 0.f;
            for (int e = 0; e < 512; ++e) s += wv[e] * out_b[e];
            bias_uv[f] = s;
        }
    } else {
        const long long total = 1081344;   // float4 quads across 6 tensors
        const long long stride = 2048LL * 256;
        for (long long i = (long long)(id - 2326) * 256 + t; i < total; i += stride) {
            const float* src; u16 *hi, *lo; long long j;
            if (i < 524288)      { src = x;  hi = xh;  lo = xl;  j = i; }
            else if (i < 557056) { src = mm; hi = mh;  lo = ml;  j = i - 524288; }
            else if (i < 688128) { src = ew; hi = ewh; lo = ewl; j = i - 557056; }
            else if (i < 884736) { src = iw; hi = iwh; lo = iwl; j = i - 688128; }
            else if (i < 950272) { src = ow; hi = owh; lo = owl; j = i - 884736; }
            else                 { src = dw; hi = dwh; lo = dwl; j = i - 950272; }
            float4 v = reinterpret_cast<const float4*>(src)[j];
            u16 h0 = bf16_rn(v.x), h1 = bf16_rn(v.y), h2 = bf16_rn(v.z), h3 = bf16_rn(v.w);
            ushort4 hv = {h0, h1, h2, h3};
            ushort4 lv = {bf16_rn(v.x - bf16_f(h0)), bf16_rn(v.y - bf16_f(h1)),
                          bf16_rn(v.z - bf16_f(h2)), bf16_rn(v.w - bf16_f(h3))};
            reinterpret_cast<ushort4*>(hi)[j] = hv;
            reinterpret_cast<ushort4*>(lo)[j] = lv;
        }
    }
}

// ===================== generalized descriptor GEMM core ====================
// C = act( (A @ B^T + bias) * scale ); omode 0=f32, 1=planes, 2=planes
// transposed (C[col*ldc+row]).  BM=128 BN=64 BK=32, 256 thr (4 waves).
struct ZD {
    const u16 *Ah, *Al, *Bh, *Bl;
    const float* bias;
    float* Cf; u16 *Ch, *Cl;
    int M, lda, ldb, ldc, K, act, omode;
    float scale;
};
template<int NZ> struct ZPack { ZD d[NZ]; };

__device__ __forceinline__ void gemm_zd(const ZD& dz, int m0, int n0,
    u16 (*Ash)[40], u16 (*Asl)[40], u16 (*Bsh)[40], u16 (*Bsl)[40])
{
    const int t  = threadIdx.x;
    const int r  = t >> 2;
    const int ck = (t & 3) << 3;
    const int lane = t & 63;
    const int wid  = t >> 6;
    const int wr = (wid >> 1) * 64;
    const int wc = (wid & 1) * 32;
    const int lr = lane & 15;
    const int lk = (lane >> 4) << 3;

    f32x4 acc[4][2];
    const f32x4 zero = {0.f, 0.f, 0.f, 0.f};
    #pragma unroll
    for (int i = 0; i < 4; ++i)
        #pragma unroll
        for (int j = 0; j < 2; ++j) acc[i][j] = zero;

    const long long arow0 = (long long)(m0 + r) * dz.lda;
    const long long arow1 = (long long)(m0 + r + 64) * dz.lda;
    const long long brow  = (long long)(n0 + r) * dz.ldb;

    for (int k0 = 0; k0 < dz.K; k0 += 32) {
        int4 vah0 = *reinterpret_cast<const int4*>(dz.Ah + arow0 + k0 + ck);
        int4 vah1 = *reinterpret_cast<const int4*>(dz.Ah + arow1 + k0 + ck);
        int4 val0 = *reinterpret_cast<const int4*>(dz.Al + arow0 + k0 + ck);
        int4 val1 = *reinterpret_cast<const int4*>(dz.Al + arow1 + k0 + ck);
        int4 vbh  = *reinterpret_cast<const int4*>(dz.Bh + brow  + k0 + ck);
        int4 vbl  = *reinterpret_cast<const int4*>(dz.Bl + brow  + k0 + ck);
        __syncthreads();
        *reinterpret_cast<int4*>(&Ash[r][ck])      = vah0;
        *reinterpret_cast<int4*>(&Ash[r + 64][ck]) = vah1;
        *reinterpret_cast<int4*>(&Asl[r][ck])      = val0;
        *reinterpret_cast<int4*>(&Asl[r + 64][ck]) = val1;
        *reinterpret_cast<int4*>(&Bsh[r][ck])      = vbh;
        *reinterpret_cast<int4*>(&Bsl[r][ck])      = vbl;
        __syncthreads();

        short8 fah[4], fal[4], fbh[2], fbl[2];
        #pragma unroll
        for (int i = 0; i < 4; ++i) {
            fah[i] = *reinterpret_cast<const short8*>(&Ash[wr + i * 16 + lr][lk]);
            fal[i] = *reinterpret_cast<const short8*>(&Asl[wr + i * 16 + lr][lk]);
        }
        #pragma unroll
        for (int j = 0; j < 2; ++j) {
            fbh[j] = *reinterpret_cast<const short8*>(&Bsh[wc + j * 16 + lr][lk]);
            fbl[j] = *reinterpret_cast<const short8*>(&Bsl[wc + j * 16 + lr][lk]);
        }
        #pragma unroll
        for (int i = 0; i < 4; ++i)
            #pragma unroll
            for (int j = 0; j < 2; ++j) {
                acc[i][j] = __builtin_amdgcn_mfma_f32_16x16x32_bf16(fah[i], fbh[j], acc[i][j], 0, 0, 0);
                acc[i][j] = __builtin_amdgcn_mfma_f32_16x16x32_bf16(fah[i], fbl[j], acc[i][j], 0, 0, 0);
                acc[i][j] = __builtin_amdgcn_mfma_f32_16x16x32_bf16(fal[i], fbh[j], acc[i][j], 0, 0, 0);
            }
    }

    #pragma unroll
    for (int j = 0; j < 2; ++j) {
        const int col = n0 + wc + j * 16 + lr;
        const float bv = dz.bias ? dz.bias[col] : 0.f;
        #pragma unroll
        for (int i = 0; i < 4; ++i) {
            #pragma unroll
            for (int q = 0; q < 4; ++q) {
                const int row = m0 + wr + i * 16 + ((lane >> 4) << 2) + q;
                float v = (acc[i][j][q] + bv) * dz.scale;
                if (dz.act) v = tanhf(v);
                if (dz.omode == 0) {
                    dz.Cf[(long long)row * dz.ldc + col] = v;
                } else {
                    long long off = (dz.omode == 1)
                        ? (long long)row * dz.ldc + col
                        : (long long)col * dz.ldc + row;
                    u16 h = bf16_rn(v);
                    dz.Ch[off] = h;
                    dz.Cl[off] = bf16_rn(v - bf16_f(h));
                }
            }
        }
    }
}

template<int NZ>
__global__ __launch_bounds__(256)
void gemm_multi(ZPack<NZ> pk)
{
    __shared__ u16 Ash[128][40];
    __shared__ u16 Asl[128][40];
    __shared__ u16 Bsh[64][40];
    __shared__ u16 Bsl[64][40];
    const ZD dz = pk.d[blockIdx.z];
    const int m0 = blockIdx.x * 128;
    if (m0 >= dz.M) return;
    gemm_zd(dz, m0, blockIdx.y * 64, Ash, Asl, Bsh, Bsl);
}

// ======================= fused attention (device body) =====================
// 128 q-rows x 256 keys x 64 d; K in 2 halves; PV in 4 key-quarters; 72KB LDS.
// MODE 0: Q = qp1 [q][2048][512] slice, rows=q*16+bb; epilogue q-mean.
// MODE 1: Q = qp2 [2048][512]; epilogue +uv.
template<int MODE>
__device__ __forceinline__ void attn_body(char* smem, int bxblk, int h,
    const u16* __restrict__ Qph, const u16* __restrict__ Qpl,
    const u16* __restrict__ Kvh, const u16* __restrict__ Kvl,
    const u16* __restrict__ VTh, const u16* __restrict__ VTl,
    const float* __restrict__ uv, u16* __restrict__ Oh, u16* __restrict__ Ol)
{
    const int t = threadIdx.x;
    const int lane = t & 63, w = t >> 6;
    const int l15 = lane & 15, g = lane >> 4;
    const int wr = w * 32;
    const int b0 = bxblk * (MODE == 0 ? 16 : 128);

    u16* Qs = (u16*)smem;            // [2][128][72] = 36864 B
    char* KsB = smem + 36864;        // [2][128][72] u16 = 36864 B

    for (int c = t; c < 2048; c += 256) {
        int plane = c >> 10, rem = c & 1023;
        int row = rem >> 3, seg = rem & 7;
        const u16* src = plane ? Qpl : Qph;
        long long addr;
        if (MODE == 0) {
            int q = row >> 4, bb = row & 15;
            addr = ((long long)q * 2048 + b0 + bb) * 512 + h * 64 + seg * 8;
        } else {
            addr = (long long)(b0 + row) * 512 + h * 64 + seg * 8;
        }
        *(int4*)(&Qs[plane * 9216 + row * 72 + seg * 8]) = *(const int4*)(src + addr);
    }

    f32x4 sacc[2][16];
    const f32x4 zero = {0.f, 0.f, 0.f, 0.f};
    #pragma unroll
    for (int i = 0; i < 2; ++i)
        #pragma unroll
        for (int j = 0; j < 16; ++j) sacc[i][j] = zero;

    short8 qfh[2][2], qfl[2][2];

    for (int kh = 0; kh < 2; ++kh) {
        if (kh) __syncthreads();
        for (int c = t; c < 2048; c += 256) {
            int plane = c >> 10, rem = c & 1023;
            int key = rem >> 3, seg = rem & 7;
            const u16* src = plane ? Kvl : Kvh;
            *(int4*)(KsB + plane * 18432 + key * 144 + seg * 16) =
                *(const int4*)(src + (long long)(kh * 128 + key) * 1024 + h * 64 + seg * 8);
        }
        __syncthreads();
        if (kh == 0) {
            #pragma unroll
            for (int i = 0; i < 2; ++i)
                #pragma unroll
                for (int kf = 0; kf < 2; ++kf) {
                    int ro = (wr + 16 * i + l15) * 72 + kf * 32 + g * 8;
                    qfh[i][kf] = *(const short8*)(&Qs[ro]);
                    qfl[i][kf] = *(const short8*)(&Qs[9216 + ro]);
                }
        }
        #pragma unroll
        for (int j = 0; j < 8; ++j) {
            int jg = kh * 8 + j;
            #pragma unroll
            for (int kf = 0; kf < 2; ++kf) {
                const char* kb = KsB + (j * 16 + l15) * 144 + (kf * 32 + g * 8) * 2;
                short8 kbh = *(const short8*)(kb);
                short8 kbl = *(const short8*)(kb + 18432);
                #pragma unroll
                for (int i = 0; i < 2; ++i) {
                    sacc[i][jg] = __builtin_amdgcn_mfma_f32_16x16x32_bf16(qfh[i][kf], kbh, sacc[i][jg], 0, 0, 0);
                    sacc[i][jg] = __builtin_amdgcn_mfma_f32_16x16x32_bf16(qfh[i][kf], kbl, sacc[i][jg], 0, 0, 0);
                    sacc[i][jg] = __builtin_amdgcn_mfma_f32_16x16x32_bf16(qfl[i][kf], kbh, sacc[i][jg], 0, 0, 0);
                }
            }
        }
    }

    float inv[2][4];
    #pragma unroll
    for (int i = 0; i < 2; ++i)
        #pragma unroll
        for (int q = 0; q < 4; ++q) {
            float m = -1e30f;
            #pragma unroll
            for (int j = 0; j < 16; ++j) m = fmaxf(m, sacc[i][j][q]);
            #pragma unroll
            for (int off = 1; off <= 8; off <<= 1) m = fmaxf(m, __shfl_xor(m, off, 64));
            #pragma unroll
            for (int j = 0; j < 16; ++j) sacc[i][j][q] = __expf(sacc[i][j][q] - m);
            float s = 0.f;
            #pragma unroll
            for (int j = 0; j < 16; ++j) s += sacc[i][j][q];
            #pragma unroll
            for (int off = 1; off <= 8; off <<= 1) s += __shfl_xor(s, off, 64);
            inv[i][q] = 1.0f / s;
        }

    f32x4 ctx[2][4];
    #pragma unroll
    for (int i = 0; i < 2; ++i)
        #pragma unroll
        for (int jd = 0; jd < 4; ++jd) ctx[i][jd] = zero;

    for (int qt = 0; qt < 4; ++qt) {
        __syncthreads();
        #pragma unroll
        for (int i = 0; i < 2; ++i)
            #pragma unroll
            for (int jj = 0; jj < 4; ++jj) {
                int jg = qt * 4 + jj;
                #pragma unroll
                for (int q = 0; q < 4; ++q) {
                    int row = wr + 16 * i + 4 * g + q;
                    int key = jj * 16 + l15;
                    float pv = sacc[i][jg][q];
                    u16 ph = bf16_rn(pv);
                    u16 pl = bf16_rn(pv - bf16_f(ph));
                    int byt = row * 128 + ((key * 2) ^ ((row & 7) << 4));
                    *(u16*)(smem + byt) = ph;
                    *(u16*)(smem + 16384 + byt) = pl;
                }
            }
        for (int c = t; c < 1024; c += 256) {
            int plane = c >> 9, rem = c & 511;
            int d = rem >> 3, seg = rem & 7;
            const u16* src = plane ? VTl : VTh;
            int4 v = *(const int4*)(src + (long long)h * 16384 + d * 256 + qt * 64 + seg * 8);
            int byt = 36864 + plane * 8192 + d * 128 + ((seg * 16) ^ ((d & 7) << 4));
            *(int4*)(smem + byt) = v;
        }
        __syncthreads();

        short8 pah[2][2], pal[2][2];
        #pragma unroll
        for (int i = 0; i < 2; ++i)
            #pragma unroll
            for (int kf = 0; kf < 2; ++kf) {
                int row = wr + 16 * i + l15;
                int byt = row * 128 + ((kf * 64 + g * 16) ^ ((row & 7) << 4));
                pah[i][kf] = *(const short8*)(smem + byt);
                pal[i][kf] = *(const short8*)(smem + 16384 + byt);
            }
        #pragma unroll
        for (int jd = 0; jd < 4; ++jd) {
            #pragma unroll
            for (int kf = 0; kf < 2; ++kf) {
                int d = 16 * jd + l15;
                int byt = 36864 + d * 128 + ((kf * 64 + g * 16) ^ ((d & 7) << 4));
                short8 vbh = *(const short8*)(smem + byt);
                short8 vbl = *(const short8*)(smem + 8192 + byt);
                #pragma unroll
                for (int i = 0; i < 2; ++i) {
                    ctx[i][jd] = __builtin_amdgcn_mfma_f32_16x16x32_bf16(pah[i][kf], vbh, ctx[i][jd], 0, 0, 0);
                    ctx[i][jd] = __builtin_amdgcn_mfma_f32_16x16x32_bf16(pah[i][kf], vbl, ctx[i][jd], 0, 0, 0);
                    ctx[i][jd] = __builtin_amdgcn_mfma_f32_16x16x32_bf16(pal[i][kf], vbh, ctx[i][jd], 0, 0, 0);
                }
            }
        }
    }

    if (MODE == 0) {
        __syncthreads();
        float* R = (float*)smem;   // [8 q][16 b][64 d] = 32 KB
        #pragma unroll
        for (int i = 0; i < 2; ++i)
            #pragma unroll
            for (int jd = 0; jd < 4; ++jd)
                #pragma unroll
                for (int q = 0; q < 4; ++q) {
                    int qa = 2 * w + i;
                    int bb = 4 * g + q;
                    int d  = 16 * jd + l15;
                    R[qa * 1024 + bb * 64 + d] = ctx[i][jd][q] * inv[i][q];
                }
        __syncthreads();
        for (int o = t; o < 1024; o += 256) {
            int bb = o >> 6, d = o & 63;
            float s = 0.f;
            #pragma unroll
            for (int qa = 0; qa < 8; ++qa) s += R[qa * 1024 + bb * 64 + d];
            s *= 0.125f;
            long long addr = (long long)(b0 + bb) * 512 + h * 64 + d;
            u16 hh = bf16_rn(s);
            Oh[addr] = hh;
            Ol[addr] = bf16_rn(s - bf16_f(hh));
        }
    } else {
        #pragma unroll
        for (int i = 0; i < 2; ++i)
            #pragma unroll
            for (int jd = 0; jd < 4; ++jd)
                #pragma unroll
                for (int q = 0; q < 4; ++q) {
                    int b = b0 + wr + 16 * i + 4 * g + q;
                    int d = 16 * jd + l15;
                    long long addr = (long long)b * 512 + h * 64 + d;
                    float v = ctx[i][jd][q] * inv[i][q] + uv[addr];
                    u16 hh = bf16_rn(v);
                    Oh[addr] = hh;
                    Ol[addr] = bf16_rn(v - bf16_f(hh));
                }
    }
}

template<int MODE>
__global__ __launch_bounds__(256, 2)
void fused_attn(const u16* __restrict__ Qph, const u16* __restrict__ Qpl,
                const u16* __restrict__ Kvh, const u16* __restrict__ Kvl,
                const u16* __restrict__ VTh, const u16* __restrict__ VTl,
                const float* __restrict__ uv,
                u16* __restrict__ Oh, u16* __restrict__ Ol)
{
    extern __shared__ char smem[];
    attn_body<MODE>(smem, blockIdx.x, blockIdx.y, Qph, Qpl, Kvh, Kvl,
                    VTh, VTl, uv, Oh, Ol);
}

// ------ half of the out1 write: quads [half*33554432, +33554432) -----------
__device__ __forceinline__ void write_half(int wb, int half,
    const float* __restrict__ mem, const float* __restrict__ u,
    float* __restrict__ out1)
{
    const float4* m4 = reinterpret_cast<const float4*>(mem);
    const float4* u4 = reinterpret_cast<const float4*>(u);
    float4* o4 = reinterpret_cast<float4*>(out1);
    long long i0 = (long long)half * 33554432 + (long long)wb * 16384 + threadIdx.x;
    #pragma unroll 4
    for (int j = 0; j < 64; ++j) {
        long long i = i0 + j * 256;
        int e4 = (int)(i & 127);
        int m  = (int)((i >> 7) & 255);
        long long b = i >> 15;
        float4 a = m4[m * 128 + e4];
        float4 c = u4[b * 128 + e4];
        float4 rr = {a.x + c.x, a.y + c.y, a.z + c.z, a.w + c.w};
        o4[i] = rr;
    }
}

// ============ launch A: fused_attn<1> (128 blocks) + write half 0 ==========
__global__ __launch_bounds__(256, 2)
void attn1_write(const u16* __restrict__ Qph, const u16* __restrict__ Qpl,
                 const u16* __restrict__ Kvh, const u16* __restrict__ Kvl,
                 const u16* __restrict__ VTh, const u16* __restrict__ VTl,
                 const float* __restrict__ uv,
                 u16* __restrict__ Oh, u16* __restrict__ Ol,
                 const float* __restrict__ mem, const float* __restrict__ uf,
                 float* __restrict__ out1)
{
    extern __shared__ char smem[];
    const int id = blockIdx.x;
    if (id < 128) {
        attn_body<1>(smem, id >> 3, id & 7, Qph, Qpl, Kvh, Kvl, VTh, VTl,
                     uv, Oh, Ol);
    } else {
        write_half(id - 128, 0, mem, uf, out1);
    }
}

// ======== launch B: final GEMM (256 blocks) + write half 1 =================
__global__ __launch_bounds__(256)
void final_write(const u16* __restrict__ c2h, const u16* __restrict__ c2l,
                 const u16* __restrict__ W2h, const u16* __restrict__ W2l,
                 const float* __restrict__ bias2, float* __restrict__ out,
                 const float* __restrict__ mem, const float* __restrict__ uf,
                 float* __restrict__ out1)
{
    __shared__ u16 Ash[128][40];
    __shared__ u16 Asl[128][40];
    __shared__ u16 Bsh[64][40];
    __shared__ u16 Bsl[64][40];
    const int id = blockIdx.x;
    if (id < 256) {
        ZD dz = { c2h, c2l, W2h, W2l, bias2, out, nullptr, nullptr,
                  2048, 512, 512, 1024, 512, 0, 0, 1.0f };
        gemm_zd(dz, (id & 15) * 128, (id >> 4) * 64, Ash, Asl, Bsh, Bsl);
    } else {
        write_half(id - 256, 1, mem, uf, out1);
    }
}

extern "C" void kernel_launch(void* const* d_in, const int* in_sizes, int n_in,
                              void* d_out, int out_size, void* d_ws, size_t ws_size,
                              hipStream_t stream)
{
    (void)in_sizes; (void)n_in; (void)out_size; (void)ws_size;
    const float* x     = (const float*)d_in[0];
    const float* mem   = (const float*)d_in[1];
    const float* enc_w = (const float*)d_in[2];
    const float* enc_b = (const float*)d_in[3];
    const float* blk_w = (const float*)d_in[4];
    const float* blk_b = (const float*)d_in[5];
    const float* in_w  = (const float*)d_in[6];
    const float* in_b  = (const float*)d_in[7];
    const float* out_w = (const float*)d_in[8];
    const float* out_b = (const float*)d_in[9];
    const float* dec_w = (const float*)d_in[10];
    const float* dec_b = (const float*)d_in[11];
    float* out = (float*)d_out;

    // ---------------- workspace carve-up (256B-aligned) --------------------
    char* p = (char*)d_ws;
    auto alloc = [&](size_t bytes) { char* q = p; p += (bytes + 255) & ~(size_t)255; return q; };
    u16* xh   = (u16*)alloc(2097152 * 2); u16* xl   = (u16*)alloc(2097152 * 2);
    u16* memh = (u16*)alloc(131072 * 2);  u16* meml = (u16*)alloc(131072 * 2);
    u16* ewh  = (u16*)alloc(524288 * 2);  u16* ewl  = (u16*)alloc(524288 * 2);
    u16* iwh  = (u16*)alloc(786432 * 2);  u16* iwl  = (u16*)alloc(786432 * 2);
    u16* owh  = (u16*)alloc(262144 * 2);  u16* owl  = (u16*)alloc(262144 * 2);
    u16* owTh = (u16*)alloc(262144 * 2);  u16* owTl = (u16*)alloc(262144 * 2);
    u16* dwh  = (u16*)alloc(524288 * 2);  u16* dwl  = (u16*)alloc(524288 * 2);
    u16* ench = (u16*)alloc(1048576 * 2); u16* encl = (u16*)alloc(1048576 * 2);
    u16* kvh  = (u16*)alloc(262144 * 2);  u16* kvl  = (u16*)alloc(262144 * 2);
    u16* vpTh = (u16*)alloc(131072 * 2);  u16* vpTl = (u16*)alloc(131072 * 2);
    float* bias1  = (float*)alloc(4096 * 4);
    float* bias2  = (float*)alloc(1024 * 4);
    float* biasuv = (float*)alloc(512 * 4);
    u16* cbh  = (u16*)alloc(1048576 * 2); u16* cbl  = (u16*)alloc(1048576 * 2);
    float* uf = (float*)alloc(1048576 * 4);
    u16* qp2h = (u16*)alloc(1048576 * 2); u16* qp2l = (u16*)alloc(1048576 * 2);
    float* uvb = (float*)alloc(1048576 * 4);
    u16* c2h  = (u16*)alloc(1048576 * 2); u16* c2l  = (u16*)alloc(1048576 * 2);
    u16* W2h  = (u16*)alloc(524288 * 2);  u16* W2l  = (u16*)alloc(524288 * 2);
    u16* Wuvh = (u16*)alloc(262144 * 2);  u16* Wuvl = (u16*)alloc(262144 * 2);

    // ------ big scratch in the not-yet-written updated_memory region -------
    float* out1 = out + 2097152;
    u16* bwTh = (u16*)out1;               // [8][512][512]
    u16* bwTl = bwTh + 2097152;
    u16* W1h  = bwTl + 2097152;           // [8][512][512]
    u16* W1l  = W1h + 2097152;
    u16* qp1h = W1l + 2097152;            // [8][2048][512]
    u16* qp1l = qp1h + 8388608;

    dim3 blk(256);

    // 1. prep: split + transposes + folded biases
    prep_all<<<dim3(4374), blk, 0, stream>>>(x, mem, enc_w, in_w, out_w, dec_w,
        blk_w, in_b, blk_b, out_b, dec_b,
        xh, xl, memh, meml, ewh, ewl, iwh, iwl, owh, owl, dwh, dwl,
        bwTh, bwTl, owTh, owTl, bias1, bias2, biasuv);

    // 2. z=14 batch: enc, W1 x8, Wuv, W2 x2, kv(wk), vpT(wv transposed)
    {
        ZPack<14> pk;
        pk.d[0] = { xh, xl, ewh, ewl, enc_b, nullptr, ench, encl,
                    2048, 1024, 1024, 512, 1024, 1, 1, 1.0f };
        for (int z = 0; z < 8; ++z)
            pk.d[1 + z] = { iwh, iwl, bwTh + (long long)z * 262144, bwTl + (long long)z * 262144,
                            nullptr, nullptr, W1h + (long long)z * 262144, W1l + (long long)z * 262144,
                            512, 512, 512, 512, 512, 0, 1, 1.0f };
        pk.d[9]  = { iwh + 1024 * 512, iwl + 1024 * 512, owTh, owTl, nullptr,
                     nullptr, Wuvh, Wuvl, 512, 512, 512, 512, 512, 0, 1, 1.0f };
        pk.d[10] = { dwh, dwl, owTh, owTl, nullptr, nullptr, W2h, W2l,
                     512, 512, 512, 512, 512, 0, 1, 1.0f };
        pk.d[11] = { dwh + 512 * 512, dwl + 512 * 512, owTh, owTl, nullptr,
                     nullptr, W2h + 512 * 512, W2l + 512 * 512,
                     512, 512, 512, 512, 512, 0, 1, 1.0f };
        pk.d[12] = { memh, meml, iwh + 512 * 512, iwl + 512 * 512, in_b + 512,
                     nullptr, kvh, kvl, 256, 512, 512, 1024, 512, 0, 1, 1.0f };
        pk.d[13] = { memh, meml, iwh + 1024 * 512, iwl + 1024 * 512, in_b + 1024,
                     nullptr, vpTh, vpTl, 256, 512, 512, 256, 512, 0, 2, 1.0f };
        gemm_multi<14><<<dim3(16, 8, 14), blk, 0, stream>>>(pk);
    }
    // 3. qp1 x8 + qp2   (z=9, 0.125 folded)
    {
        ZPack<9> pk;
        for (int z = 0; z < 8; ++z)
            pk.d[z] = { ench, encl, W1h + (long long)z * 262144, W1l + (long long)z * 262144,
                        bias1 + z * 512, nullptr,
                        qp1h + (long long)z * 1048576, qp1l + (long long)z * 1048576,
                        2048, 512, 512, 512, 512, 0, 1, 0.125f };
        pk.d[8] = { ench, encl, iwh, iwl, in_b, nullptr, qp2h, qp2l,
                    2048, 512, 512, 512, 512, 0, 1, 0.125f };
        gemm_multi<9><<<dim3(16, 8, 9), blk, 0, stream>>>(pk);
    }
    // 4. fused MHA1 -> cbar planes
    fused_attn<0><<<dim3(128, 8), blk, 73728, stream>>>(qp1h, qp1l, kvh, kvl,
        vpTh, vpTl, nullptr, cbh, cbl);
    // 5. u (f32) + uvb (f32), batched
    {
        ZPack<2> pk;
        pk.d[0] = { cbh, cbl, owh, owl, out_b, uf, nullptr, nullptr,
                    2048, 512, 512, 512, 512, 0, 0, 1.0f };
        pk.d[1] = { cbh, cbl, Wuvh, Wuvl, biasuv, uvb, nullptr, nullptr,
                    2048, 512, 512, 512, 512, 0, 0, 1.0f };
        gemm_multi<2><<<dim3(16, 8, 2), blk, 0, stream>>>(pk);
    }
    // 6. fused MHA2 (+uv) -> c2 planes, co-scheduled with out1 write half 0
    //    (qp1/W1/bwT scratch in out1 region is dead after step 4)
    attn1_write<<<dim3(2176), blk, 73728, stream>>>(qp2h, qp2l, kvh, kvl,
        vpTh, vpTl, uvb, c2h, c2l, mem, uf, out1);
    // 7. output = c2 @ W2^T + bias2, co-scheduled with out1 write half 1
    final_write<<<dim3(2304), blk, 0, stream>>>(c2h, c2l, W2h, W2l, bias2, out,
        mem, uf, out1);
}